// Round 1
// baseline (309.265 us; speedup 1.0000x reference)
//
#include <hip/hip_runtime.h>
#include <cstdint>
#include <cstddef>

// R1: exact JAX threefry reproduction + analytic reward collapse.
// PARTITIONABLE=1 -> modern JAX (jax_threefry_partitionable=True, default >=0.5.0)
#define PARTITIONABLE 1

__device__ __forceinline__ void tf2x32(uint32_t k0, uint32_t k1, uint32_t& x0, uint32_t& x1){
  const uint32_t k2 = k0 ^ k1 ^ 0x1BD11BDAu;
  x0 += k0; x1 += k1;
#define TFR(r) { x0 += x1; x1 = (x1<<(r))|(x1>>(32-(r))); x1 ^= x0; }
  TFR(13) TFR(15) TFR(26) TFR(6)
  x0 += k1; x1 += k2 + 1u;
  TFR(17) TFR(29) TFR(16) TFR(24)
  x0 += k2; x1 += k0 + 2u;
  TFR(13) TFR(15) TFR(26) TFR(6)
  x0 += k0; x1 += k1 + 3u;
  TFR(17) TFR(29) TFR(16) TFR(24)
  x0 += k1; x1 += k2 + 4u;
  TFR(13) TFR(15) TFR(26) TFR(6)
  x0 += k2; x1 += k0 + 5u;
#undef TFR
}

// correctly-rounded f32 log via f64 (OCML log f64 <=1 ulp_f64 -> CR f32 w.p. 1-2^-28)
__device__ __forceinline__ float crlogf(float x){
  return (float)log((double)x);
}

// ---------------- kernel 1: sampling -----------------------------------
// thread = (n, pixel); loops s = 0..9. Writes 2-bit class planes (ballot-packed)
// into ws and zeroes all of out.
__global__ __launch_bounds__(256) void k_sample(const float* __restrict__ prob,
                                                unsigned long long* __restrict__ planes,
                                                float* __restrict__ out)
{
  const int tid  = blockIdx.x * 256 + threadIdx.x;   // (n<<16)|pix , 524288 total
  const int pix  = tid & 0xFFFF;
  const int n    = tid >> 16;
  const int lane = threadIdx.x & 63;

  // logits = log(prob + 1e-12) == log(prob) exactly in f32 (prob >= 1e-3)
  float lg[4];
#pragma unroll
  for (int c = 0; c < 4; ++c)
    lg[c] = crlogf(prob[(((n<<2)|c) << 16) | pix]);

#if PARTITIONABLE
  // fold-like split: subkey_s = threefry((0,42), (0, s))
  uint32_t a0 = 0u, a1 = (uint32_t)lane;
  tf2x32(0u, 42u, a0, a1);
#else
  // original split: out_flat = threefry((0,42), iota(20)) blocks (k,k+10)
  uint32_t e0 = (lane < 10) ? (uint32_t)lane : (uint32_t)(lane - 10);
  uint32_t e1 = (lane < 10) ? (uint32_t)(lane + 10) : (uint32_t)lane;
  tf2x32(0u, 42u, e0, e1);
  uint32_t ofl = (lane < 10) ? e0 : e1;
#endif

#pragma unroll 1
  for (int s = 0; s < 10; ++s){
#if PARTITIONABLE
    const uint32_t k0 = (uint32_t)__shfl((int)a0, s, 64);
    const uint32_t k1 = (uint32_t)__shfl((int)a1, s, 64);
#else
    const uint32_t k0 = (uint32_t)__shfl((int)ofl, 2*s,   64);
    const uint32_t k1 = (uint32_t)__shfl((int)ofl, 2*s+1, 64);
#endif
    float best = -3.0e38f; int bc = 0;
#pragma unroll
    for (int c = 0; c < 4; ++c){
      const uint32_t j = (uint32_t)((((n<<2)|c) << 16) | pix); // flat idx in (n,c,h,w)
      uint32_t bits;
#if PARTITIONABLE
      { uint32_t x0 = 0u, x1 = j;            // counter = (hi,lo) = (0, j)
        tf2x32(k0, k1, x0, x1);
        bits = x0 ^ x1; }                    // 32-bit fold
#else
      { const uint32_t H = 1u << 20;         // half of 2^21 elements
        uint32_t x0 = (j < H) ? j : (j - H);
        uint32_t x1 = (j < H) ? (j + H) : j;
        tf2x32(k0, k1, x0, x1);
        bits = (j < H) ? x0 : x1; }
#endif
      const uint32_t m = bits >> 9;
      // u = max(tiny, (bitcast(0x3f800000|m)-1) * (1-tiny) + tiny)  ==  m?m*2^-23:tiny
      const float u = m ? (float)m * 0x1p-23f : 1.17549435e-38f;
      const float w = -crlogf(u);
      const float g = -crlogf(w);            // gumbel
      const float sc = g + lg[c];
      if (sc > best){ best = sc; bc = c; }   // strict > == jnp.argmax first-max
    }
    const int gid = ((n * 10 + s) << 16) | pix;
    out[gid] = 0.0f;                         // class-0 pixels stay 0
    const unsigned long long b0 = __ballot(bc & 1);
    const unsigned long long b1 = __ballot(bc & 2);
    if (lane == 0){
      planes[((size_t)(gid >> 6) << 1) + 0] = b0;
      planes[((size_t)(gid >> 6) << 1) + 1] = b1;
    }
  }
}

// ---------------- kernel 2: per (sample, class) reward ------------------
__device__ __forceinline__ int win5pop(const unsigned long long* W, int x){
  const int i = x - 2;
  unsigned long long v;
  if (i < 0) v = (W[0] << (-i));
  else {
    const int w = i >> 6, sh = i & 63;
    v = W[w] >> sh;
    if (sh && w < 3) v |= W[w+1] << (64 - sh);
  }
  return __popcll(v & 31ull);
}

__global__ __launch_bounds__(256) void k_reward(const unsigned long long* __restrict__ planes,
                                                const float* __restrict__ prob,
                                                float* __restrict__ out)
{
  const int b   = blockIdx.x;        // 0..239
  const int ns  = b / 3;             // n*10 + s
  const int cls = (b % 3) + 1;       // 1..3
  const int n   = ns / 10;
  const int t   = threadIdx.x;       // row id 0..255

  __shared__ unsigned long long fgS[256][4], fillS[256][4], expS[256][4];
  __shared__ unsigned long long bestKey;
  __shared__ int flag;

  // build fg bitmap for row t from 2-bit planes
  const unsigned long long c0 = (unsigned long long)(cls & 1);
  const unsigned long long c1 = (unsigned long long)((cls >> 1) & 1);
  unsigned long long fg[4];
  {
    const size_t base = (size_t)((ns << 10) | (t << 2));
#pragma unroll
    for (int w = 0; w < 4; ++w){
      const unsigned long long p0 = planes[(base + w)*2 + 0];
      const unsigned long long p1 = planes[(base + w)*2 + 1];
      fg[w] = (c0 ? p0 : ~p0) & (c1 ? p1 : ~p1);
      fgS[t][w] = fg[w];
    }
  }
  if (t == 0){ flag = 0; bestKey = 0ull; }
  __syncthreads();
  if (fg[0] | fg[1] | fg[2] | fg[3]) flag = 1;   // benign race
  __syncthreads();
  if (!flag) return;   // empty fg: contribution is identically 0

  // count = sumpool5x5(fg)*fg ; argmax with first-index tie-break
  unsigned long long myKey = 0ull;
#pragma unroll 1
  for (int w = 0; w < 4; ++w){
    unsigned long long rem = fg[w];
    while (rem){
      const int k = __builtin_ctzll(rem);
      rem &= rem - 1;
      const int x = (w << 6) | k;
      int cnt = 0;
#pragma unroll
      for (int dy = -2; dy <= 2; ++dy){
        const int r = t + dy;
        if (r < 0 || r > 255) continue;
        cnt += win5pop(fgS[r], x);
      }
      const unsigned idx = (unsigned)((t << 8) | x);
      const unsigned long long key =
          ((unsigned long long)cnt << 32) | (unsigned long long)(0xFFFFFFFFu - idx);
      if (key > myKey) myKey = key;
    }
  }
  atomicMax(&bestKey, myKey);
  __syncthreads();
  const int seedIdx = (int)(0xFFFFFFFFu - (unsigned)(bestKey & 0xFFFFFFFFull));
  const int srow = seedIdx >> 8, scol = seedIdx & 255;

  // flood fill (8-connected, synchronous Jacobi on bitmaps)
#pragma unroll
  for (int w = 0; w < 4; ++w) fillS[t][w] = 0ull;
  if (t == srow) fillS[t][scol >> 6] = 1ull << (scol & 63);

  for (;;){
    __syncthreads();
    if (t == 0) flag = 0;
    const unsigned long long f0 = fillS[t][0], f1 = fillS[t][1],
                             f2 = fillS[t][2], f3 = fillS[t][3];
    expS[t][0] = f0 | (f0<<1) | (f0>>1) | (f1<<63);
    expS[t][1] = f1 | (f1<<1) | (f1>>1) | (f0>>63) | (f2<<63);
    expS[t][2] = f2 | (f2<<1) | (f2>>1) | (f1>>63) | (f3<<63);
    expS[t][3] = f3 | (f3<<1) | (f3>>1) | (f2>>63);
    __syncthreads();
    bool ch = false;
#pragma unroll
    for (int w = 0; w < 4; ++w){
      unsigned long long e = expS[t][w];
      if (t > 0)   e |= expS[t-1][w];
      if (t < 255) e |= expS[t+1][w];
      const unsigned long long nf = fgS[t][w] & e;
      ch |= (nf != fillS[t][w]);
      fillS[t][w] = nf;
    }
    if (ch) flag = 1;
    __syncthreads();
    if (!flag) break;
  }

  // write: fg & in-component -> -p ; fg & outside -> +p ; else untouched (0)
  const float* pb = prob + ((size_t)(((n << 2) | cls)) << 16);
  float* ob = out + ((size_t)ns << 16);
  const int word = t >> 6, bit = t & 63;
#pragma unroll 1
  for (int r = 0; r < 256; ++r){
    if ((fgS[r][word] >> bit) & 1ull){
      const int idx = (r << 8) | t;
      const float p = pb[idx];
      ob[idx] = ((fillS[r][word] >> bit) & 1ull) ? -p : p;
    }
  }
}

extern "C" void kernel_launch(void* const* d_in, const int* in_sizes, int n_in,
                              void* d_out, int out_size, void* d_ws, size_t ws_size,
                              hipStream_t stream)
{
  const float* prob = (const float*)d_in[0];
  float* out = (float*)d_out;
  unsigned long long* planes = (unsigned long long*)d_ws;  // needs 1.25 MiB

  k_sample<<<2048, 256, 0, stream>>>(prob, planes, out);
  k_reward<<<240,  256, 0, stream>>>(planes, prob, out);
}

// Round 2
// 237.970 us; speedup vs baseline: 1.2996x; 1.2996x over previous
//
#include <hip/hip_runtime.h>
#include <cstdint>
#include <cstddef>

typedef unsigned long long u64;

// ---------------- threefry2x32 (20 rounds) ------------------------------
__device__ __forceinline__ void tf2x32(uint32_t k0, uint32_t k1, uint32_t& x0, uint32_t& x1){
  const uint32_t k2 = k0 ^ k1 ^ 0x1BD11BDAu;
  x0 += k0; x1 += k1;
#define TFR(r) { x0 += x1; x1 = (x1<<(r))|(x1>>(32-(r))); x1 ^= x0; }
  TFR(13) TFR(15) TFR(26) TFR(6)
  x0 += k1; x1 += k2 + 1u;
  TFR(17) TFR(29) TFR(16) TFR(24)
  x0 += k2; x1 += k0 + 2u;
  TFR(13) TFR(15) TFR(26) TFR(6)
  x0 += k0; x1 += k1 + 3u;
  TFR(17) TFR(29) TFR(16) TFR(24)
  x0 += k1; x1 += k2 + 4u;
  TFR(13) TFR(15) TFR(26) TFR(6)
  x0 += k2; x1 += k0 + 5u;
#undef TFR
}

// correctly-rounded f32 log via f64 (matches reference; proven by R1 absmax=0)
__device__ __forceinline__ float crlogf(float x){
  return (float)log((double)x);
}

// ---------------- kernel 1: sampling -----------------------------------
__global__ __launch_bounds__(256) void k_sample(const float* __restrict__ prob,
                                                u64* __restrict__ planes,
                                                float* __restrict__ out)
{
  const int tid  = blockIdx.x * 256 + threadIdx.x;   // (n<<16)|pix
  const int pix  = tid & 0xFFFF;
  const int n    = tid >> 16;
  const int lane = threadIdx.x & 63;

  float lg[4];
#pragma unroll
  for (int c = 0; c < 4; ++c)
    lg[c] = crlogf(prob[(((n<<2)|c) << 16) | pix]);

  // partitionable split: subkey_s = threefry((0,42), (0,s))
  uint32_t a0 = 0u, a1 = (uint32_t)lane;
  tf2x32(0u, 42u, a0, a1);

#pragma unroll 1
  for (int s = 0; s < 10; ++s){
    const uint32_t k0 = (uint32_t)__shfl((int)a0, s, 64);
    const uint32_t k1 = (uint32_t)__shfl((int)a1, s, 64);

    uint32_t mv[4];
    bool bad = false;
    float b1 = -3.0e38f, b2 = -3.0e38f; int bc = 0;
#pragma unroll
    for (int c = 0; c < 4; ++c){
      const uint32_t j = (uint32_t)((((n<<2)|c) << 16) | pix);
      uint32_t x0 = 0u, x1 = j;
      tf2x32(k0, k1, x0, x1);
      const uint32_t m = (x0 ^ x1) >> 9;
      mv[c] = m;
      // danger zone: m==0 (tiny path) or u too close to 1 (cancellation in log)
      bad = bad || (m == 0u) || (m >= 0x7FF000u);
      // fast gumbel score: g = -ln(-ln(u)), via v_log_f32
      const float u = (float)m * 0x1p-23f;
      const float w = __log2f(u) * (-0.69314718055994531f);   // -ln(u)
      const float g = __log2f(w) * (-0.69314718055994531f);   // -ln(w)
      const float sc = g + lg[c];
      if (sc > b1){ b2 = b1; b1 = sc; bc = c; }
      else if (sc > b2) b2 = sc;
    }
    // fallback: exact (bit-identical to R1) when margin too small or draw flagged
    if (bad || (b1 - b2) < 1e-3f){
      float best = -3.0e38f; bc = 0;
#pragma unroll
      for (int c = 0; c < 4; ++c){
        const uint32_t m = mv[c];
        const float u = m ? (float)m * 0x1p-23f : 1.17549435e-38f;
        const float w = -crlogf(u);
        const float g = -crlogf(w);
        const float sc = g + lg[c];
        if (sc > best){ best = sc; bc = c; }
      }
    }

    const int gid = ((n * 10 + s) << 16) | pix;
    out[gid] = 0.0f;
    const u64 b0 = __ballot(bc & 1);
    const u64 b1m = __ballot(bc & 2);
    if (lane == 0){
      planes[((size_t)(gid >> 6) << 1) + 0] = b0;
      planes[((size_t)(gid >> 6) << 1) + 1] = b1m;
    }
  }
}

// ---------------- kernel 2: per (sample, class) reward ------------------
// LDS stride 5 u64 (40B) -> 4-way max bank aliasing instead of 16-way.

__device__ __forceinline__ int win5pop(const u64* W, int x){
  const int i = x - 2;
  u64 v;
  if (i < 0) v = W[0] << (-i);
  else {
    const int w = i >> 6, sh = i & 63;
    v = W[w] >> sh;
    if (sh) v |= W[w+1] << (64 - sh);    // W[4] is zero pad
  }
  return __popcll(v & 31ull);
}

// 256-bit add with carry propagation (o = a + b)
__device__ __forceinline__ void add256(const u64 a[4], const u64 b[4], u64 o[4]){
  u64 c = 0;
#pragma unroll
  for (int w = 0; w < 4; ++w){
    const u64 t = a[w] + c;
    const u64 c1 = (t < c) ? 1ull : 0ull;
    const u64 s = t + b[w];
    const u64 c2 = (s < t) ? 1ull : 0ull;
    o[w] = s;
    c = c1 | c2;
  }
}

// fill whole runs of m that contain any seed bit of s (s must be subset of m)
__device__ __forceinline__ void runfill(const u64 m[4], const u64 s[4], u64 o[4]){
  u64 A[4];
  add256(m, s, A);                       // up: [lowest seed .. run top]
  u64 rm[4], rs[4], RA[4];
#pragma unroll
  for (int w = 0; w < 4; ++w){ rm[w] = __brevll(m[3-w]); rs[w] = __brevll(s[3-w]); }
  add256(rm, rs, RA);                    // down via bit-reversal
#pragma unroll
  for (int w = 0; w < 4; ++w){
    const u64 up  = (A[w]  ^ m[w])  & m[w];
    const u64 rdn = (RA[3-w] ^ rm[3-w]) & rm[3-w];
    o[w] = s[w] | up | __brevll(rdn);
  }
}

__global__ __launch_bounds__(256) void k_reward(const u64* __restrict__ planes,
                                                const float* __restrict__ prob,
                                                float* __restrict__ out)
{
  const int b   = blockIdx.x;        // 0..239
  const int ns  = b / 3;             // n*10 + s
  const int cls = (b % 3) + 1;       // 1..3
  const int n   = ns / 10;
  const int t   = threadIdx.x;       // row 0..255

  __shared__ u64 fgS[256*5];         // [row][word], word 4 = zero pad
  __shared__ u64 fillS[258*5];       // +2 guard rows (0 and 257)
  __shared__ u64 bestKey;
  __shared__ int flag;

  const u64 c0 = (u64)(cls & 1);
  const u64 c1 = (u64)((cls >> 1) & 1);
  u64 fg[4];
  {
    const size_t base = (size_t)((ns << 10) | (t << 2));
#pragma unroll
    for (int w = 0; w < 4; ++w){
      const u64 p0 = planes[(base + w)*2 + 0];
      const u64 p1 = planes[(base + w)*2 + 1];
      fg[w] = (c0 ? p0 : ~p0) & (c1 ? p1 : ~p1);
      fgS[t*5 + w] = fg[w];
    }
    fgS[t*5 + 4] = 0ull;
  }
  if (t == 0){ flag = 0; bestKey = 0ull; }
  if (t < 2){
    const int gr = (t == 0) ? 0 : 257;
#pragma unroll
    for (int w = 0; w < 5; ++w) fillS[gr*5 + w] = 0ull;
  }
  __syncthreads();
  if (fg[0] | fg[1] | fg[2] | fg[3]) flag = 1;   // benign race
  __syncthreads();
  if (!flag) return;                              // empty fg: contribution 0

  // ---- seed: argmax of sumpool5(fg)*fg, first-index tie-break ----
  u64 myKey = 0ull;
#pragma unroll 1
  for (int w = 0; w < 4; ++w){
    u64 rem = fg[w];
    while (rem){
      const int k = __builtin_ctzll(rem);
      rem &= rem - 1;
      const int x = (w << 6) | k;
      int cnt = 0;
#pragma unroll
      for (int dy = -2; dy <= 2; ++dy){
        const int r = t + dy;
        if (r < 0 || r > 255) continue;
        cnt += win5pop(&fgS[r*5], x);
      }
      const unsigned idx = (unsigned)((t << 8) | x);
      const u64 key = ((u64)cnt << 32) | (u64)(0xFFFFFFFFu - idx);
      if (key > myKey) myKey = key;
    }
  }
#pragma unroll
  for (int off = 32; off; off >>= 1){
    const u64 o = (u64)__shfl_xor((long long)myKey, off, 64);
    if (o > myKey) myKey = o;
  }
  if ((t & 63) == 0) atomicMax(&bestKey, myKey);
  __syncthreads();
  const int seedIdx = (int)(0xFFFFFFFFu - (unsigned)(bestKey & 0xFFFFFFFFull));
  const int srow = seedIdx >> 8, scol = seedIdx & 255;

  // ---- scanline flood fill (run-parallel) ----
  u64 f[4] = {0ull,0ull,0ull,0ull};
  if (t == srow) f[scol >> 6] = 1ull << (scol & 63);
#pragma unroll
  for (int w = 0; w < 4; ++w) fillS[(t+1)*5 + w] = f[w];
  if (t == 0) flag = 0;

  for (;;){
    __syncthreads();   // fillS (and flag reset) visible
    u64 U[4], S[4], nf[4];
#pragma unroll
    for (int w = 0; w < 4; ++w)
      U[w] = fillS[t*5 + w] | fillS[(t+1)*5 + w] | fillS[(t+2)*5 + w];
    S[0] = U[0] | (U[0]<<1) | (U[0]>>1) | (U[1]<<63);
    S[1] = U[1] | (U[1]<<1) | (U[1]>>1) | (U[0]>>63) | (U[2]<<63);
    S[2] = U[2] | (U[2]<<1) | (U[2]>>1) | (U[1]>>63) | (U[3]<<63);
    S[3] = U[3] | (U[3]<<1) | (U[3]>>1) | (U[2]>>63);
#pragma unroll
    for (int w = 0; w < 4; ++w) S[w] &= fg[w];
    runfill(fg, S, nf);
    bool ch = false;
#pragma unroll
    for (int w = 0; w < 4; ++w){ ch |= (nf[w] != f[w]); f[w] = nf[w]; }
    __syncthreads();   // all reads of old fillS done
#pragma unroll
    for (int w = 0; w < 4; ++w) fillS[(t+1)*5 + w] = f[w];
    if (ch) flag = 1;
    __syncthreads();   // writes + flag visible
    if (!flag) break;
    if (t == 0) flag = 0;
  }

  // ---- write: fg&fill -> -p ; fg&~fill -> +p ----
  const float* pb = prob + ((size_t)(((n << 2) | cls)) << 16);
  float* ob = out + ((size_t)ns << 16);
  const int word = t >> 6, bit = t & 63;
#pragma unroll 1
  for (int r = 0; r < 256; ++r){
    const u64 fgw = fgS[r*5 + word];
    if ((fgw >> bit) & 1ull){
      const int idx = (r << 8) | t;
      const float p = pb[idx];
      ob[idx] = ((fillS[(r+1)*5 + word] >> bit) & 1ull) ? -p : p;
    }
  }
}

extern "C" void kernel_launch(void* const* d_in, const int* in_sizes, int n_in,
                              void* d_out, int out_size, void* d_ws, size_t ws_size,
                              hipStream_t stream)
{
  const float* prob = (const float*)d_in[0];
  float* out = (float*)d_out;
  u64* planes = (u64*)d_ws;   // 1.31 MiB

  k_sample<<<2048, 256, 0, stream>>>(prob, planes, out);
  k_reward<<<240,  256, 0, stream>>>(planes, prob, out);
}

// Round 3
// 140.156 us; speedup vs baseline: 2.2066x; 1.6979x over previous
//
#include <hip/hip_runtime.h>
#include <cstdint>
#include <cstddef>

typedef unsigned long long u64;

// ---------------- threefry2x32 (20 rounds) ------------------------------
__device__ __forceinline__ void tf2x32(uint32_t k0, uint32_t k1, uint32_t& x0, uint32_t& x1){
  const uint32_t k2 = k0 ^ k1 ^ 0x1BD11BDAu;
  x0 += k0; x1 += k1;
#define TFR(r) { x0 += x1; x1 = (x1<<(r))|(x1>>(32-(r))); x1 ^= x0; }
  TFR(13) TFR(15) TFR(26) TFR(6)
  x0 += k1; x1 += k2 + 1u;
  TFR(17) TFR(29) TFR(16) TFR(24)
  x0 += k2; x1 += k0 + 2u;
  TFR(13) TFR(15) TFR(26) TFR(6)
  x0 += k0; x1 += k1 + 3u;
  TFR(17) TFR(29) TFR(16) TFR(24)
  x0 += k1; x1 += k2 + 4u;
  TFR(13) TFR(15) TFR(26) TFR(6)
  x0 += k2; x1 += k0 + 5u;
#undef TFR
}

// correctly-rounded f32 log via f64 (reference-exact; proven R1/R2 absmax=0)
__device__ __forceinline__ float crlogf(float x){
  return (float)log((double)x);
}

// ---------------- kernel 1: sampling -----------------------------------
__global__ __launch_bounds__(256) void k_sample(const float* __restrict__ prob,
                                                u64* __restrict__ planes)
{
  const int tid  = blockIdx.x * 256 + threadIdx.x;   // (n<<16)|pix
  const int pix  = tid & 0xFFFF;
  const int n    = tid >> 16;
  const int lane = threadIdx.x & 63;

  float p[4], lgf[4];
#pragma unroll
  for (int c = 0; c < 4; ++c){
    p[c] = prob[(((n<<2)|c) << 16) | pix];
    lgf[c] = __log2f(p[c]) * 0.69314718055994531f;   // fast ln(p)
  }

  // partitionable split: subkey_s = threefry((0,42), (0,s))
  uint32_t a0 = 0u, a1 = (uint32_t)lane;
  tf2x32(0u, 42u, a0, a1);

#pragma unroll 1
  for (int s = 0; s < 10; ++s){
    const uint32_t k0 = (uint32_t)__shfl((int)a0, s, 64);
    const uint32_t k1 = (uint32_t)__shfl((int)a1, s, 64);

    uint32_t mv[4];
    bool bad = false;
    float b1 = -3.0e38f, b2 = -3.0e38f; int bc = 0;
#pragma unroll
    for (int c = 0; c < 4; ++c){
      const uint32_t j = (uint32_t)((((n<<2)|c) << 16) | pix);
      uint32_t x0 = 0u, x1 = j;
      tf2x32(k0, k1, x0, x1);
      const uint32_t m = (x0 ^ x1) >> 9;
      mv[c] = m;
      bad = bad || (m == 0u) || (m >= 0x7FF000u);    // same guards as R2 (validated)
      const float u = (float)m * 0x1p-23f;
      const float w = __log2f(u) * (-0.69314718055994531f);   // -ln(u)
      const float g = __log2f(w) * (-0.69314718055994531f);   // gumbel
      const float sc = g + lgf[c];
      if (sc > b1){ b2 = b1; b1 = sc; bc = c; }
      else if (sc > b2) b2 = sc;
    }
    // exact fallback (bit-identical to R1's all-exact path)
    if (bad || (b1 - b2) < 1e-3f){
      float best = -3.0e38f; bc = 0;
#pragma unroll
      for (int c = 0; c < 4; ++c){
        const uint32_t m = mv[c];
        const float u = m ? (float)m * 0x1p-23f : 1.17549435e-38f;
        const float w = -crlogf(u);
        const float g = -crlogf(w);
        const float sc = g + crlogf(p[c]);
        if (sc > best){ best = sc; bc = c; }
      }
    }

    const int gid = ((n * 10 + s) << 16) | pix;
    const u64 b0 = __ballot(bc & 1);
    const u64 b1m = __ballot(bc & 2);
    if (lane == 0){
      planes[((size_t)(gid >> 6) << 1) + 0] = b0;
      planes[((size_t)(gid >> 6) << 1) + 1] = b1m;
    }
  }
}

// ---------------- kernel 2: fill-bitmap computation ---------------------
__device__ __forceinline__ int pop5w(u64 wm1, u64 w0, u64 wp1, int k){
  u64 v;
  if (k >= 2){
    const int sh = k - 2;
    v = w0 >> sh;
    if (sh) v |= wp1 << (64 - sh);
  } else {
    v = (w0 << (2 - k)) | (wm1 >> (62 + k));
  }
  return __popcll(v & 31ull);
}

__device__ __forceinline__ void add256(const u64 a[4], const u64 b[4], u64 o[4]){
  u64 c = 0;
#pragma unroll
  for (int w = 0; w < 4; ++w){
    const u64 t = a[w] + c;
    const u64 c1 = (t < c) ? 1ull : 0ull;
    const u64 s = t + b[w];
    const u64 c2 = (s < t) ? 1ull : 0ull;
    o[w] = s;
    c = c1 | c2;
  }
}

// fill whole runs of m containing seed bits of s (s subset of m)
__device__ __forceinline__ void runfill(const u64 m[4], const u64 s[4], u64 o[4]){
  u64 A[4];
  add256(m, s, A);
  u64 rm[4], rs[4], RA[4];
#pragma unroll
  for (int w = 0; w < 4; ++w){ rm[w] = __brevll(m[3-w]); rs[w] = __brevll(s[3-w]); }
  add256(rm, rs, RA);
#pragma unroll
  for (int w = 0; w < 4; ++w){
    const u64 up  = (A[w] ^ m[w]) & m[w];
    const u64 rdn = (RA[3-w] ^ rm[3-w]) & rm[3-w];
    o[w] = s[w] | up | __brevll(rdn);
  }
}

__global__ __launch_bounds__(256) void k_reward(const u64* __restrict__ planes,
                                                u64* __restrict__ fillB)
{
  const int b   = blockIdx.x;        // 0..239
  const int ns  = b / 3;             // n*10 + s
  const int cls = (b % 3) + 1;       // 1..3
  const int t   = threadIdx.x;       // row 0..255

  __shared__ u64 fgS[256*5];         // [row][word], word 4 = zero pad
  __shared__ u64 fillS[258*5];       // +2 guard rows
  __shared__ u64 bestKey;
  __shared__ int flag;

  const u64 c0 = (u64)(cls & 1);
  const u64 c1 = (u64)((cls >> 1) & 1);
  u64 fg[4];
  {
    const size_t base = (size_t)((ns << 10) | (t << 2));
#pragma unroll
    for (int w = 0; w < 4; ++w){
      const u64 p0 = planes[(base + w)*2 + 0];
      const u64 p1 = planes[(base + w)*2 + 1];
      fg[w] = (c0 ? p0 : ~p0) & (c1 ? p1 : ~p1);
      fgS[t*5 + w] = fg[w];
    }
    fgS[t*5 + 4] = 0ull;
  }
  if (t == 0){ flag = 0; bestKey = 0ull; }
  if (t < 2){
    const int gr = (t == 0) ? 0 : 257;
#pragma unroll
    for (int w = 0; w < 5; ++w) fillS[gr*5 + w] = 0ull;
  }
  __syncthreads();
  if (fg[0] | fg[1] | fg[2] | fg[3]) flag = 1;   // benign race
  __syncthreads();
  if (!flag) return;                 // empty fg: k_write never reads this bitmap

  // ---- preload 5 neighbor rows into registers ----
  u64 N[5][5];
#pragma unroll
  for (int dy = 0; dy < 5; ++dy){
    const int r = t + dy - 2;
    const bool ok = (r >= 0) && (r < 256);
    const int rr = ok ? r : t;
#pragma unroll
    for (int w = 0; w < 4; ++w) N[dy][w] = ok ? fgS[rr*5 + w] : 0ull;
    N[dy][4] = 0ull;
  }

  // ---- seed: argmax of sumpool5(fg)*fg, first-index tie-break ----
  u64 myKey = 0ull;
#pragma unroll
  for (int w = 0; w < 4; ++w){
    u64 rem = fg[w];
    while (rem){
      const int k = __builtin_ctzll(rem);
      rem &= rem - 1;
      int cnt = 0;
#pragma unroll
      for (int dy = 0; dy < 5; ++dy)
        cnt += pop5w(w ? N[dy][w-1] : 0ull, N[dy][w], N[dy][w+1], k);
      const unsigned idx = (unsigned)((t << 8) | (w << 6) | k);
      const u64 key = ((u64)cnt << 32) | (u64)(0xFFFFFFFFu - idx);
      if (key > myKey) myKey = key;
    }
  }
#pragma unroll
  for (int off = 32; off; off >>= 1){
    const u64 o = (u64)__shfl_xor((long long)myKey, off, 64);
    if (o > myKey) myKey = o;
  }
  if ((t & 63) == 0) atomicMax(&bestKey, myKey);
  __syncthreads();
  const int seedIdx = (int)(0xFFFFFFFFu - (unsigned)(bestKey & 0xFFFFFFFFull));
  const int srow = seedIdx >> 8, scol = seedIdx & 255;

  // ---- scanline flood fill ----
  u64 f[4] = {0ull,0ull,0ull,0ull};
  if (t == srow) f[scol >> 6] = 1ull << (scol & 63);
#pragma unroll
  for (int w = 0; w < 4; ++w) fillS[(t+1)*5 + w] = f[w];
  if (t == 0) flag = 0;

  for (;;){
    __syncthreads();
    u64 U[4], S[4], nf[4];
#pragma unroll
    for (int w = 0; w < 4; ++w)
      U[w] = fillS[t*5 + w] | fillS[(t+1)*5 + w] | fillS[(t+2)*5 + w];
    S[0] = U[0] | (U[0]<<1) | (U[0]>>1) | (U[1]<<63);
    S[1] = U[1] | (U[1]<<1) | (U[1]>>1) | (U[0]>>63) | (U[2]<<63);
    S[2] = U[2] | (U[2]<<1) | (U[2]>>1) | (U[1]>>63) | (U[3]<<63);
    S[3] = U[3] | (U[3]<<1) | (U[3]>>1) | (U[2]>>63);
#pragma unroll
    for (int w = 0; w < 4; ++w) S[w] &= fg[w];
    runfill(fg, S, nf);
    bool ch = false;
#pragma unroll
    for (int w = 0; w < 4; ++w){ ch |= (nf[w] != f[w]); f[w] = nf[w]; }
    __syncthreads();
#pragma unroll
    for (int w = 0; w < 4; ++w) fillS[(t+1)*5 + w] = f[w];
    if (ch) flag = 1;
    __syncthreads();
    if (!flag) break;
    if (t == 0) flag = 0;
  }

  // ---- dump fill bitmap: [nsc][row][4 words], coalesced ----
  const int nsc = ns*3 + (cls - 1);
  u64* fb = fillB + (((size_t)nsc) << 10) + (t << 2);
#pragma unroll
  for (int w = 0; w < 4; ++w) fb[w] = f[w];
}

// ---------------- kernel 3: output write --------------------------------
__global__ __launch_bounds__(256) void k_write(const u64* __restrict__ planes,
                                               const u64* __restrict__ fillB,
                                               const float* __restrict__ prob,
                                               float* __restrict__ out)
{
  const int T = blockIdx.x * 256 + threadIdx.x;    // 524288 threads
  const int lane = T & 63;
#pragma unroll
  for (int i = 0; i < 10; ++i){
    const int g  = i * 524288 + T;                 // < 2^23
    const int wi = g >> 6;                         // wave-uniform
    const u64 pw0 = planes[(size_t)wi*2 + 0];
    const u64 pw1 = planes[(size_t)wi*2 + 1];
    const int ns = g >> 16;
    const int n  = ns / 10;
    const int pp = g & 0xFFFF;
    const int fwi = pp >> 6;
    const u64 f1 = fillB[(((size_t)(ns*3 + 0)) << 10) | fwi];
    const u64 f2 = fillB[(((size_t)(ns*3 + 1)) << 10) | fwi];
    const u64 f3 = fillB[(((size_t)(ns*3 + 2)) << 10) | fwi];
    const float pa = prob[(size_t)((((n<<2)|1) << 16) | pp)];
    const float pb = prob[(size_t)((((n<<2)|2) << 16) | pp)];
    const float pc = prob[(size_t)((((n<<2)|3) << 16) | pp)];
    const int cls = (int)((pw0 >> lane) & 1ull) | (((int)((pw1 >> lane) & 1ull)) << 1);
    const u64   fw = (cls == 1) ? f1 : ((cls == 2) ? f2 : f3);
    const float p  = (cls == 1) ? pa : ((cls == 2) ? pb : pc);
    const uint32_t sgn = ((uint32_t)((fw >> lane) & 1ull)) << 31;
    float o = __uint_as_float(__float_as_uint(p) ^ sgn);
    if (cls == 0) o = 0.0f;
    out[g] = o;
  }
}

extern "C" void kernel_launch(void* const* d_in, const int* in_sizes, int n_in,
                              void* d_out, int out_size, void* d_ws, size_t ws_size,
                              hipStream_t stream)
{
  const float* prob = (const float*)d_in[0];
  float* out = (float*)d_out;
  u64* planes = (u64*)d_ws;            // 163840 u64 = 1.31 MB
  u64* fillB  = planes + 163840;       // 245760 u64 = 1.97 MB

  k_sample<<<2048, 256, 0, stream>>>(prob, planes);
  k_reward<<<240,  256, 0, stream>>>(planes, fillB);
  k_write <<<2048, 256, 0, stream>>>(planes, fillB, prob, out);
}

// Round 4
// 116.489 us; speedup vs baseline: 2.6549x; 1.2032x over previous
//
#include <hip/hip_runtime.h>
#include <cstdint>
#include <cstddef>

typedef unsigned long long u64;

// ---------------- threefry2x32 (20 rounds) ------------------------------
__host__ __device__ constexpr void tf2x32(uint32_t k0, uint32_t k1, uint32_t& x0, uint32_t& x1){
  const uint32_t k2 = k0 ^ k1 ^ 0x1BD11BDAu;
  x0 += k0; x1 += k1;
#define TFR(r) { x0 += x1; x1 = (x1<<(r))|(x1>>(32-(r))); x1 ^= x0; }
  TFR(13) TFR(15) TFR(26) TFR(6)
  x0 += k1; x1 += k2 + 1u;
  TFR(17) TFR(29) TFR(16) TFR(24)
  x0 += k2; x1 += k0 + 2u;
  TFR(13) TFR(15) TFR(26) TFR(6)
  x0 += k0; x1 += k1 + 3u;
  TFR(17) TFR(29) TFR(16) TFR(24)
  x0 += k1; x1 += k2 + 4u;
  TFR(13) TFR(15) TFR(26) TFR(6)
  x0 += k2; x1 += k0 + 5u;
#undef TFR
}

// subkeys for s=0..9: threefry((0,42),(0,s)) — input-independent constants
struct Keys { uint32_t k0[10]; uint32_t k1[10]; };
constexpr Keys make_keys(){
  Keys K{};
  for (int s = 0; s < 10; ++s){
    uint32_t x0 = 0u, x1 = (uint32_t)s;
    tf2x32(0u, 42u, x0, x1);
    K.k0[s] = x0; K.k1[s] = x1;
  }
  return K;
}
__constant__ constexpr Keys KEYS = make_keys();

// correctly-rounded f32 log via f64 (reference-exact; proven R1-R3 absmax=0)
__device__ __forceinline__ float crlogf(float x){
  return (float)log((double)x);
}

// ---------------- kernel 1: sampling -----------------------------------
__global__ __launch_bounds__(256) void k_sample(const float* __restrict__ prob,
                                                u64* __restrict__ planes)
{
  const int tid  = blockIdx.x * 256 + threadIdx.x;   // (n<<16)|pix
  const int pix  = tid & 0xFFFF;
  const int n    = tid >> 16;
  const int lane = threadIdx.x & 63;

  float p[4], lgf[4];
#pragma unroll
  for (int c = 0; c < 4; ++c){
    p[c] = prob[(((n<<2)|c) << 16) | pix];
    lgf[c] = __log2f(p[c]) * 0.69314718055994531f;   // fast ln(p), err ~1.2e-6
  }

#pragma unroll 1
  for (int s = 0; s < 10; ++s){
    const uint32_t k0 = KEYS.k0[s];
    const uint32_t k1 = KEYS.k1[s];

    uint32_t mv[4];
    float b1 = -3.0e38f, b2 = -3.0e38f; int bc = 0;
#pragma unroll
    for (int c = 0; c < 4; ++c){
      const uint32_t j = (uint32_t)((((n<<2)|c) << 16) | pix);
      uint32_t x0 = 0u, x1 = j;
      tf2x32(k0, k1, x0, x1);
      const uint32_t m = (x0 ^ x1) >> 9;
      mv[c] = m;
      // w = -ln(u), u = m*2^-23 (or 2^-126 if m==0)
      const float u = m ? (float)m * 0x1p-23f : 1.17549435e-38f;
      const float wl = __log2f(u) * (-0.69314718055994531f);
      // near-1 branchless poly: e = 1-u exact; -ln(1-e) = e*(1+e/2+...+e^9*(1/10))
      const float e = (float)(0x800000u - m) * 0x1p-23f;     // exact for m>0
      float t = 0.1f;
      t = fmaf(t, e, 0.11111111f);
      t = fmaf(t, e, 0.125f);
      t = fmaf(t, e, 0.14285715f);
      t = fmaf(t, e, 0.16666667f);
      t = fmaf(t, e, 0.2f);
      t = fmaf(t, e, 0.25f);
      t = fmaf(t, e, 0.33333334f);
      t = fmaf(t, e, 0.5f);
      t = fmaf(t, e, 1.0f);
      const float wp = e * t;                                 // rel err < 3e-7 for e<=0.25
      const float w  = (m >= 0x600000u) ? wp : wl;            // u >= 0.75 -> poly
      const float g  = __log2f(w) * (-0.69314718055994531f);  // gumbel
      const float sc = g + lgf[c];
      if (sc > b1){ b2 = b1; b1 = sc; bc = c; }
      else if (sc > b2) b2 = sc;
    }
    // exact fallback (bit-identical to R1's all-exact path); fast-path score
    // error <= ~3.4e-6 << tau/2, so argmax provably unchanged when margin >= tau
    if ((b1 - b2) < 1e-4f){
      float best = -3.0e38f; bc = 0;
#pragma unroll
      for (int c = 0; c < 4; ++c){
        const uint32_t m = mv[c];
        const float u = m ? (float)m * 0x1p-23f : 1.17549435e-38f;
        const float w = -crlogf(u);
        const float g = -crlogf(w);
        const float sc = g + crlogf(p[c]);
        if (sc > best){ best = sc; bc = c; }
      }
    }

    const int gid = ((n * 10 + s) << 16) | pix;
    const u64 bb0 = __ballot(bc & 1);
    const u64 bb1 = __ballot(bc & 2);
    if (lane == 0){
      planes[((size_t)(gid >> 6) << 1) + 0] = bb0;
      planes[((size_t)(gid >> 6) << 1) + 1] = bb1;
    }
  }
}

// ---------------- kernel 2: fill-bitmap computation ---------------------
__device__ __forceinline__ int pop5w(u64 wm1, u64 w0, u64 wp1, int k){
  u64 v;
  if (k >= 2){
    const int sh = k - 2;
    v = w0 >> sh;
    if (sh) v |= wp1 << (64 - sh);
  } else {
    v = (w0 << (2 - k)) | (wm1 >> (62 + k));
  }
  return __popcll(v & 31ull);
}

__device__ __forceinline__ void add256(const u64 a[4], const u64 b[4], u64 o[4]){
  u64 c = 0;
#pragma unroll
  for (int w = 0; w < 4; ++w){
    const u64 t = a[w] + c;
    const u64 c1 = (t < c) ? 1ull : 0ull;
    const u64 s = t + b[w];
    const u64 c2 = (s < t) ? 1ull : 0ull;
    o[w] = s;
    c = c1 | c2;
  }
}

// fill whole runs of m containing seed bits of s (s subset of m)
__device__ __forceinline__ void runfill(const u64 m[4], const u64 s[4], u64 o[4]){
  u64 A[4];
  add256(m, s, A);
  u64 rm[4], rs[4], RA[4];
#pragma unroll
  for (int w = 0; w < 4; ++w){ rm[w] = __brevll(m[3-w]); rs[w] = __brevll(s[3-w]); }
  add256(rm, rs, RA);
#pragma unroll
  for (int w = 0; w < 4; ++w){
    const u64 up  = (A[w] ^ m[w]) & m[w];
    const u64 rdn = (RA[3-w] ^ rm[3-w]) & rm[3-w];
    o[w] = s[w] | up | __brevll(rdn);
  }
}

__global__ __launch_bounds__(256) void k_reward(const u64* __restrict__ planes,
                                                u64* __restrict__ fillB)
{
  const int b   = blockIdx.x;        // 0..239
  const int ns  = b / 3;             // n*10 + s
  const int cls = (b % 3) + 1;       // 1..3
  const int t   = threadIdx.x;       // row 0..255

  __shared__ u64 fgS[256*5];         // [row][word], word 4 = zero pad
  __shared__ u64 fillS[258*5];       // +2 guard rows
  __shared__ u64 bestKey;
  __shared__ int flag;

  const u64 c0 = (u64)(cls & 1);
  const u64 c1 = (u64)((cls >> 1) & 1);
  u64 fg[4];
  {
    const size_t base = (size_t)((ns << 10) | (t << 2));
#pragma unroll
    for (int w = 0; w < 4; ++w){
      const u64 p0 = planes[(base + w)*2 + 0];
      const u64 p1 = planes[(base + w)*2 + 1];
      fg[w] = (c0 ? p0 : ~p0) & (c1 ? p1 : ~p1);
      fgS[t*5 + w] = fg[w];
    }
    fgS[t*5 + 4] = 0ull;
  }
  if (t == 0){ flag = 0; bestKey = 0ull; }
  if (t < 2){
    const int gr = (t == 0) ? 0 : 257;
#pragma unroll
    for (int w = 0; w < 5; ++w) fillS[gr*5 + w] = 0ull;
  }
  __syncthreads();
  if (fg[0] | fg[1] | fg[2] | fg[3]) flag = 1;   // benign race
  __syncthreads();
  if (!flag) return;                 // empty fg: k_write never reads this bitmap

  // ---- preload 5 neighbor rows into registers ----
  u64 N[5][5];
#pragma unroll
  for (int dy = 0; dy < 5; ++dy){
    const int r = t + dy - 2;
    const bool ok = (r >= 0) && (r < 256);
    const int rr = ok ? r : t;
#pragma unroll
    for (int w = 0; w < 4; ++w) N[dy][w] = ok ? fgS[rr*5 + w] : 0ull;
    N[dy][4] = 0ull;
  }

  // ---- seed: argmax of sumpool5(fg)*fg, first-index tie-break ----
  u64 myKey = 0ull;
#pragma unroll
  for (int w = 0; w < 4; ++w){
    u64 rem = fg[w];
    while (rem){
      const int k = __builtin_ctzll(rem);
      rem &= rem - 1;
      int cnt = 0;
#pragma unroll
      for (int dy = 0; dy < 5; ++dy)
        cnt += pop5w(w ? N[dy][w-1] : 0ull, N[dy][w], N[dy][w+1], k);
      const unsigned idx = (unsigned)((t << 8) | (w << 6) | k);
      const u64 key = ((u64)cnt << 32) | (u64)(0xFFFFFFFFu - idx);
      if (key > myKey) myKey = key;
    }
  }
#pragma unroll
  for (int off = 32; off; off >>= 1){
    const u64 o = (u64)__shfl_xor((long long)myKey, off, 64);
    if (o > myKey) myKey = o;
  }
  if ((t & 63) == 0) atomicMax(&bestKey, myKey);
  __syncthreads();
  const int seedIdx = (int)(0xFFFFFFFFu - (unsigned)(bestKey & 0xFFFFFFFFull));
  const int srow = seedIdx >> 8, scol = seedIdx & 255;

  // ---- scanline flood fill ----
  u64 f[4] = {0ull,0ull,0ull,0ull};
  if (t == srow) f[scol >> 6] = 1ull << (scol & 63);
#pragma unroll
  for (int w = 0; w < 4; ++w) fillS[(t+1)*5 + w] = f[w];
  if (t == 0) flag = 0;

  for (;;){
    __syncthreads();
    u64 U[4], S[4], nf[4];
#pragma unroll
    for (int w = 0; w < 4; ++w)
      U[w] = fillS[t*5 + w] | fillS[(t+1)*5 + w] | fillS[(t+2)*5 + w];
    S[0] = U[0] | (U[0]<<1) | (U[0]>>1) | (U[1]<<63);
    S[1] = U[1] | (U[1]<<1) | (U[1]>>1) | (U[0]>>63) | (U[2]<<63);
    S[2] = U[2] | (U[2]<<1) | (U[2]>>1) | (U[1]>>63) | (U[3]<<63);
    S[3] = U[3] | (U[3]<<1) | (U[3]>>1) | (U[2]>>63);
#pragma unroll
    for (int w = 0; w < 4; ++w) S[w] &= fg[w];
    runfill(fg, S, nf);
    bool ch = false;
#pragma unroll
    for (int w = 0; w < 4; ++w){ ch |= (nf[w] != f[w]); f[w] = nf[w]; }
    __syncthreads();
#pragma unroll
    for (int w = 0; w < 4; ++w) fillS[(t+1)*5 + w] = f[w];
    if (ch) flag = 1;
    __syncthreads();
    if (!flag) break;
    if (t == 0) flag = 0;
  }

  // ---- dump fill bitmap: [nsc][row][4 words], coalesced ----
  const int nsc = ns*3 + (cls - 1);
  u64* fb = fillB + (((size_t)nsc) << 10) + (t << 2);
#pragma unroll
  for (int w = 0; w < 4; ++w) fb[w] = f[w];
}

// ---------------- kernel 3: output write --------------------------------
__global__ __launch_bounds__(256) void k_write(const u64* __restrict__ planes,
                                               const u64* __restrict__ fillB,
                                               const float* __restrict__ prob,
                                               float* __restrict__ out)
{
  const int T = blockIdx.x * 256 + threadIdx.x;    // 524288 threads
  const int lane = T & 63;
#pragma unroll
  for (int i = 0; i < 10; ++i){
    const int g  = i * 524288 + T;                 // < 2^23
    const int wi = g >> 6;                         // wave-uniform
    const u64 pw0 = planes[(size_t)wi*2 + 0];
    const u64 pw1 = planes[(size_t)wi*2 + 1];
    const int ns = g >> 16;
    const int n  = ns / 10;
    const int pp = g & 0xFFFF;
    const int fwi = pp >> 6;
    const u64 f1 = fillB[(((size_t)(ns*3 + 0)) << 10) | fwi];
    const u64 f2 = fillB[(((size_t)(ns*3 + 1)) << 10) | fwi];
    const u64 f3 = fillB[(((size_t)(ns*3 + 2)) << 10) | fwi];
    const float pa = prob[(size_t)((((n<<2)|1) << 16) | pp)];
    const float pb = prob[(size_t)((((n<<2)|2) << 16) | pp)];
    const float pc = prob[(size_t)((((n<<2)|3) << 16) | pp)];
    const int cls = (int)((pw0 >> lane) & 1ull) | (((int)((pw1 >> lane) & 1ull)) << 1);
    const u64   fw = (cls == 1) ? f1 : ((cls == 2) ? f2 : f3);
    const float p  = (cls == 1) ? pa : ((cls == 2) ? pb : pc);
    const uint32_t sgn = ((uint32_t)((fw >> lane) & 1ull)) << 31;
    float o = __uint_as_float(__float_as_uint(p) ^ sgn);
    if (cls == 0) o = 0.0f;
    out[g] = o;
  }
}

extern "C" void kernel_launch(void* const* d_in, const int* in_sizes, int n_in,
                              void* d_out, int out_size, void* d_ws, size_t ws_size,
                              hipStream_t stream)
{
  const float* prob = (const float*)d_in[0];
  float* out = (float*)d_out;
  u64* planes = (u64*)d_ws;            // 163840 u64 = 1.31 MB
  u64* fillB  = planes + 163840;       // 245760 u64 = 1.97 MB

  k_sample<<<2048, 256, 0, stream>>>(prob, planes);
  k_reward<<<240,  256, 0, stream>>>(planes, fillB);
  k_write <<<2048, 256, 0, stream>>>(planes, fillB, prob, out);
}

// Round 5
// 113.866 us; speedup vs baseline: 2.7160x; 1.0230x over previous
//
#include <hip/hip_runtime.h>
#include <cstdint>
#include <cstddef>

typedef unsigned long long u64;

// 1-instruction rotate: v_alignbit_b32(x,x,32-r) == rotl(x,r)
#if defined(__HIP_DEVICE_COMPILE__)
#define ROTL(x, r) __builtin_amdgcn_alignbit((x), (x), 32 - (r))
#else
#define ROTL(x, r) (((x) << (r)) | ((x) >> (32 - (r))))
#endif

// ---------------- threefry2x32 (20 rounds) ------------------------------
__device__ __forceinline__ void tf2x32(uint32_t k0, uint32_t k1, uint32_t& x0, uint32_t& x1){
  const uint32_t k2 = k0 ^ k1 ^ 0x1BD11BDAu;
  x0 += k0; x1 += k1;
#define TFR(r) { x0 += x1; x1 = ROTL(x1, r); x1 ^= x0; }
  TFR(13) TFR(15) TFR(26) TFR(6)
  x0 += k1; x1 += k2 + 1u;
  TFR(17) TFR(29) TFR(16) TFR(24)
  x0 += k2; x1 += k0 + 2u;
  TFR(13) TFR(15) TFR(26) TFR(6)
  x0 += k0; x1 += k1 + 3u;
  TFR(17) TFR(29) TFR(16) TFR(24)
  x0 += k1; x1 += k2 + 4u;
  TFR(13) TFR(15) TFR(26) TFR(6)
  x0 += k2; x1 += k0 + 5u;
#undef TFR
}

// host-constexpr copy for key table generation
constexpr void tf2x32_h(uint32_t k0, uint32_t k1, uint32_t& x0, uint32_t& x1){
  const uint32_t k2 = k0 ^ k1 ^ 0x1BD11BDAu;
  x0 += k0; x1 += k1;
#define TFR(r) { x0 += x1; x1 = ((x1<<(r))|(x1>>(32-(r)))); x1 ^= x0; }
  TFR(13) TFR(15) TFR(26) TFR(6)
  x0 += k1; x1 += k2 + 1u;
  TFR(17) TFR(29) TFR(16) TFR(24)
  x0 += k2; x1 += k0 + 2u;
  TFR(13) TFR(15) TFR(26) TFR(6)
  x0 += k0; x1 += k1 + 3u;
  TFR(17) TFR(29) TFR(16) TFR(24)
  x0 += k1; x1 += k2 + 4u;
  TFR(13) TFR(15) TFR(26) TFR(6)
  x0 += k2; x1 += k0 + 5u;
#undef TFR
}

// subkeys for s=0..9: threefry((0,42),(0,s)) — input-independent constants
struct Keys { uint32_t k0[10]; uint32_t k1[10]; };
constexpr Keys make_keys(){
  Keys K{};
  for (int s = 0; s < 10; ++s){
    uint32_t x0 = 0u, x1 = (uint32_t)s;
    tf2x32_h(0u, 42u, x0, x1);
    K.k0[s] = x0; K.k1[s] = x1;
  }
  return K;
}
__constant__ constexpr Keys KEYS = make_keys();

// correctly-rounded f32 log via f64 (reference-exact; proven R1-R4 absmax=0)
__device__ __forceinline__ float crlogf(float x){
  return (float)log((double)x);
}

// ---------------- kernel 1: sampling -----------------------------------
// argmax_c( -ln(-ln u_c) + ln p_c )  ==  argmin_c  (-ln u_c) / p_c
__global__ __launch_bounds__(256) void k_sample(const float* __restrict__ prob,
                                                u64* __restrict__ planes)
{
  const int tid  = blockIdx.x * 256 + threadIdx.x;   // (n<<16)|pix
  const int pix  = tid & 0xFFFF;
  const int n    = tid >> 16;
  const int lane = threadIdx.x & 63;

  float p[4], rp[4];
#pragma unroll
  for (int c = 0; c < 4; ++c){
    p[c]  = prob[(((n<<2)|c) << 16) | pix];
    rp[c] = __builtin_amdgcn_rcpf(p[c]);             // 1 ulp
  }

#pragma unroll 1
  for (int s = 0; s < 10; ++s){
    const uint32_t k0 = KEYS.k0[s];
    const uint32_t k1 = KEYS.k1[s];

    uint32_t mv[4];
    float b1 = 3.0e38f, b2 = 3.0e38f; int bc = 0;
#pragma unroll
    for (int c = 0; c < 4; ++c){
      const uint32_t j = (uint32_t)((((n<<2)|c) << 16) | pix);
      uint32_t x0 = 0u, x1 = j;
      tf2x32(k0, k1, x0, x1);
      const uint32_t m = (x0 ^ x1) >> 9;
      mv[c] = m;
      // w = -ln(u), u = m*2^-23 (or 2^-126 if m==0; log2 then exact = -126)
      const float u  = m ? (float)m * 0x1p-23f : 1.17549435e-38f;
      const float wl = __log2f(u) * (-0.69314718055994531f);
      // near-1: e = 1-u exact; -ln(1-e) via 10-term Taylor, rel err < 3.5e-7
      const float e = (float)(0x800000u - m) * 0x1p-23f;
      float t = 0.1f;
      t = fmaf(t, e, 0.11111111f);
      t = fmaf(t, e, 0.125f);
      t = fmaf(t, e, 0.14285715f);
      t = fmaf(t, e, 0.16666667f);
      t = fmaf(t, e, 0.2f);
      t = fmaf(t, e, 0.25f);
      t = fmaf(t, e, 0.33333334f);
      t = fmaf(t, e, 0.5f);
      t = fmaf(t, e, 1.0f);
      const float wp = e * t;
      const float w  = (m >= 0x600000u) ? wp : wl;   // u >= 0.75 -> poly
      const float q  = w * rp[c];                    // race score, rel err <= 4.5e-7
      if (q < b1){ b2 = b1; b1 = q; bc = c; }
      else if (q < b2) b2 = q;
    }
    // relative margin guard: accepted => exact ln-gap >= 1.9e-5 => ref f32
    // score gap > 0 => argmin q == reference argmax. Else: exact fallback
    // (bit-identical to R1's all-exact reference path).
    if ((b2 - b1) < 2e-5f * b2){
      float best = -3.0e38f; bc = 0;
#pragma unroll
      for (int c = 0; c < 4; ++c){
        const uint32_t m = mv[c];
        const float u = m ? (float)m * 0x1p-23f : 1.17549435e-38f;
        const float w = -crlogf(u);
        const float g = -crlogf(w);
        const float sc = g + crlogf(p[c]);
        if (sc > best){ best = sc; bc = c; }
      }
    }

    const int gid = ((n * 10 + s) << 16) | pix;
    const u64 bb0 = __ballot(bc & 1);
    const u64 bb1 = __ballot(bc & 2);
    if (lane == 0){
      planes[((size_t)(gid >> 6) << 1) + 0] = bb0;
      planes[((size_t)(gid >> 6) << 1) + 1] = bb1;
    }
  }
}

// ---------------- kernel 2: fill-bitmap computation ---------------------
__device__ __forceinline__ int pop5w(u64 wm1, u64 w0, u64 wp1, int k){
  u64 v;
  if (k >= 2){
    const int sh = k - 2;
    v = w0 >> sh;
    if (sh) v |= wp1 << (64 - sh);
  } else {
    v = (w0 << (2 - k)) | (wm1 >> (62 + k));
  }
  return __popcll(v & 31ull);
}

__device__ __forceinline__ void add256(const u64 a[4], const u64 b[4], u64 o[4]){
  u64 c = 0;
#pragma unroll
  for (int w = 0; w < 4; ++w){
    const u64 t = a[w] + c;
    const u64 c1 = (t < c) ? 1ull : 0ull;
    const u64 s = t + b[w];
    const u64 c2 = (s < t) ? 1ull : 0ull;
    o[w] = s;
    c = c1 | c2;
  }
}

// fill whole runs of m containing seed bits of s (s subset of m)
__device__ __forceinline__ void runfill(const u64 m[4], const u64 s[4], u64 o[4]){
  u64 A[4];
  add256(m, s, A);
  u64 rm[4], rs[4], RA[4];
#pragma unroll
  for (int w = 0; w < 4; ++w){ rm[w] = __brevll(m[3-w]); rs[w] = __brevll(s[3-w]); }
  add256(rm, rs, RA);
#pragma unroll
  for (int w = 0; w < 4; ++w){
    const u64 up  = (A[w] ^ m[w]) & m[w];
    const u64 rdn = (RA[3-w] ^ rm[3-w]) & rm[3-w];
    o[w] = s[w] | up | __brevll(rdn);
  }
}

__global__ __launch_bounds__(256) void k_reward(const u64* __restrict__ planes,
                                                u64* __restrict__ fillB)
{
  const int b   = blockIdx.x;        // 0..239
  const int ns  = b / 3;             // n*10 + s
  const int cls = (b % 3) + 1;       // 1..3
  const int t   = threadIdx.x;       // row 0..255

  __shared__ u64 fgS[256*5];         // [row][word], word 4 = zero pad
  __shared__ u64 fillS[258*5];       // +2 guard rows
  __shared__ u64 bestKey;
  __shared__ int flag;

  const u64 c0 = (u64)(cls & 1);
  const u64 c1 = (u64)((cls >> 1) & 1);
  u64 fg[4];
  {
    const size_t base = (size_t)((ns << 10) | (t << 2));
#pragma unroll
    for (int w = 0; w < 4; ++w){
      const u64 p0 = planes[(base + w)*2 + 0];
      const u64 p1 = planes[(base + w)*2 + 1];
      fg[w] = (c0 ? p0 : ~p0) & (c1 ? p1 : ~p1);
      fgS[t*5 + w] = fg[w];
    }
    fgS[t*5 + 4] = 0ull;
  }
  if (t == 0){ flag = 0; bestKey = 0ull; }
  if (t < 2){
    const int gr = (t == 0) ? 0 : 257;
#pragma unroll
    for (int w = 0; w < 5; ++w) fillS[gr*5 + w] = 0ull;
  }
  __syncthreads();
  if (fg[0] | fg[1] | fg[2] | fg[3]) flag = 1;   // benign race
  __syncthreads();
  if (!flag) return;                 // empty fg: k_write never reads this bitmap

  // ---- preload 5 neighbor rows into registers ----
  u64 N[5][5];
#pragma unroll
  for (int dy = 0; dy < 5; ++dy){
    const int r = t + dy - 2;
    const bool ok = (r >= 0) && (r < 256);
    const int rr = ok ? r : t;
#pragma unroll
    for (int w = 0; w < 4; ++w) N[dy][w] = ok ? fgS[rr*5 + w] : 0ull;
    N[dy][4] = 0ull;
  }

  // ---- seed: argmax of sumpool5(fg)*fg, first-index tie-break ----
  u64 myKey = 0ull;
#pragma unroll
  for (int w = 0; w < 4; ++w){
    u64 rem = fg[w];
    while (rem){
      const int k = __builtin_ctzll(rem);
      rem &= rem - 1;
      int cnt = 0;
#pragma unroll
      for (int dy = 0; dy < 5; ++dy)
        cnt += pop5w(w ? N[dy][w-1] : 0ull, N[dy][w], N[dy][w+1], k);
      const unsigned idx = (unsigned)((t << 8) | (w << 6) | k);
      const u64 key = ((u64)cnt << 32) | (u64)(0xFFFFFFFFu - idx);
      if (key > myKey) myKey = key;
    }
  }
#pragma unroll
  for (int off = 32; off; off >>= 1){
    const u64 o = (u64)__shfl_xor((long long)myKey, off, 64);
    if (o > myKey) myKey = o;
  }
  if ((t & 63) == 0) atomicMax(&bestKey, myKey);
  __syncthreads();
  const int seedIdx = (int)(0xFFFFFFFFu - (unsigned)(bestKey & 0xFFFFFFFFull));
  const int srow = seedIdx >> 8, scol = seedIdx & 255;

  // ---- scanline flood fill ----
  u64 f[4] = {0ull,0ull,0ull,0ull};
  if (t == srow) f[scol >> 6] = 1ull << (scol & 63);
#pragma unroll
  for (int w = 0; w < 4; ++w) fillS[(t+1)*5 + w] = f[w];
  if (t == 0) flag = 0;

  for (;;){
    __syncthreads();
    u64 U[4], S[4], nf[4];
#pragma unroll
    for (int w = 0; w < 4; ++w)
      U[w] = fillS[t*5 + w] | fillS[(t+1)*5 + w] | fillS[(t+2)*5 + w];
    S[0] = U[0] | (U[0]<<1) | (U[0]>>1) | (U[1]<<63);
    S[1] = U[1] | (U[1]<<1) | (U[1]>>1) | (U[0]>>63) | (U[2]<<63);
    S[2] = U[2] | (U[2]<<1) | (U[2]>>1) | (U[1]>>63) | (U[3]<<63);
    S[3] = U[3] | (U[3]<<1) | (U[3]>>1) | (U[2]>>63);
#pragma unroll
    for (int w = 0; w < 4; ++w) S[w] &= fg[w];
    runfill(fg, S, nf);
    bool ch = false;
#pragma unroll
    for (int w = 0; w < 4; ++w){ ch |= (nf[w] != f[w]); f[w] = nf[w]; }
    __syncthreads();
#pragma unroll
    for (int w = 0; w < 4; ++w) fillS[(t+1)*5 + w] = f[w];
    if (ch) flag = 1;
    __syncthreads();
    if (!flag) break;
    if (t == 0) flag = 0;
  }

  // ---- dump fill bitmap: [nsc][row][4 words], coalesced ----
  const int nsc = ns*3 + (cls - 1);
  u64* fb = fillB + (((size_t)nsc) << 10) + (t << 2);
#pragma unroll
  for (int w = 0; w < 4; ++w) fb[w] = f[w];
}

// ---------------- kernel 3: output write --------------------------------
__global__ __launch_bounds__(256) void k_write(const u64* __restrict__ planes,
                                               const u64* __restrict__ fillB,
                                               const float* __restrict__ prob,
                                               float* __restrict__ out)
{
  const int T = blockIdx.x * 256 + threadIdx.x;    // 524288 threads
  const int lane = T & 63;
#pragma unroll
  for (int i = 0; i < 10; ++i){
    const int g  = i * 524288 + T;                 // < 2^23
    const int wi = g >> 6;                         // wave-uniform
    const u64 pw0 = planes[(size_t)wi*2 + 0];
    const u64 pw1 = planes[(size_t)wi*2 + 1];
    const int ns = g >> 16;
    const int n  = ns / 10;
    const int pp = g & 0xFFFF;
    const int fwi = pp >> 6;
    const u64 f1 = fillB[(((size_t)(ns*3 + 0)) << 10) | fwi];
    const u64 f2 = fillB[(((size_t)(ns*3 + 1)) << 10) | fwi];
    const u64 f3 = fillB[(((size_t)(ns*3 + 2)) << 10) | fwi];
    const float pa = prob[(size_t)((((n<<2)|1) << 16) | pp)];
    const float pb = prob[(size_t)((((n<<2)|2) << 16) | pp)];
    const float pc = prob[(size_t)((((n<<2)|3) << 16) | pp)];
    const int cls = (int)((pw0 >> lane) & 1ull) | (((int)((pw1 >> lane) & 1ull)) << 1);
    const u64   fw = (cls == 1) ? f1 : ((cls == 2) ? f2 : f3);
    const float p  = (cls == 1) ? pa : ((cls == 2) ? pb : pc);
    const uint32_t sgn = ((uint32_t)((fw >> lane) & 1ull)) << 31;
    float o = __uint_as_float(__float_as_uint(p) ^ sgn);
    if (cls == 0) o = 0.0f;
    out[g] = o;
  }
}

extern "C" void kernel_launch(void* const* d_in, const int* in_sizes, int n_in,
                              void* d_out, int out_size, void* d_ws, size_t ws_size,
                              hipStream_t stream)
{
  const float* prob = (const float*)d_in[0];
  float* out = (float*)d_out;
  u64* planes = (u64*)d_ws;            // 163840 u64 = 1.31 MB
  u64* fillB  = planes + 163840;       // 245760 u64 = 1.97 MB

  k_sample<<<2048, 256, 0, stream>>>(prob, planes);
  k_reward<<<240,  256, 0, stream>>>(planes, fillB);
  k_write <<<2048, 256, 0, stream>>>(planes, fillB, prob, out);
}

// Round 6
// 90.733 us; speedup vs baseline: 3.4085x; 1.2550x over previous
//
#include <hip/hip_runtime.h>
#include <cstdint>
#include <cstddef>

typedef unsigned long long u64;

// 1-instruction rotate
#if defined(__HIP_DEVICE_COMPILE__)
#define ROTL(x, r) __builtin_amdgcn_alignbit((x), (x), 32 - (r))
#else
#define ROTL(x, r) (((x) << (r)) | ((x) >> (32 - (r))))
#endif

// ---------------- threefry2x32 (20 rounds) ------------------------------
__device__ __forceinline__ void tf2x32(uint32_t k0, uint32_t k1, uint32_t& x0, uint32_t& x1){
  const uint32_t k2 = k0 ^ k1 ^ 0x1BD11BDAu;
  x0 += k0; x1 += k1;
#define TFR(r) { x0 += x1; x1 = ROTL(x1, r); x1 ^= x0; }
  TFR(13) TFR(15) TFR(26) TFR(6)
  x0 += k1; x1 += k2 + 1u;
  TFR(17) TFR(29) TFR(16) TFR(24)
  x0 += k2; x1 += k0 + 2u;
  TFR(13) TFR(15) TFR(26) TFR(6)
  x0 += k0; x1 += k1 + 3u;
  TFR(17) TFR(29) TFR(16) TFR(24)
  x0 += k1; x1 += k2 + 4u;
  TFR(13) TFR(15) TFR(26) TFR(6)
  x0 += k2; x1 += k0 + 5u;
#undef TFR
}

constexpr void tf2x32_h(uint32_t k0, uint32_t k1, uint32_t& x0, uint32_t& x1){
  const uint32_t k2 = k0 ^ k1 ^ 0x1BD11BDAu;
  x0 += k0; x1 += k1;
#define TFR(r) { x0 += x1; x1 = ((x1<<(r))|(x1>>(32-(r)))); x1 ^= x0; }
  TFR(13) TFR(15) TFR(26) TFR(6)
  x0 += k1; x1 += k2 + 1u;
  TFR(17) TFR(29) TFR(16) TFR(24)
  x0 += k2; x1 += k0 + 2u;
  TFR(13) TFR(15) TFR(26) TFR(6)
  x0 += k0; x1 += k1 + 3u;
  TFR(17) TFR(29) TFR(16) TFR(24)
  x0 += k1; x1 += k2 + 4u;
  TFR(13) TFR(15) TFR(26) TFR(6)
  x0 += k2; x1 += k0 + 5u;
#undef TFR
}

struct Keys { uint32_t k0[10]; uint32_t k1[10]; };
constexpr Keys make_keys(){
  Keys K{};
  for (int s = 0; s < 10; ++s){
    uint32_t x0 = 0u, x1 = (uint32_t)s;
    tf2x32_h(0u, 42u, x0, x1);
    K.k0[s] = x0; K.k1[s] = x1;
  }
  return K;
}
__constant__ constexpr Keys KEYS = make_keys();

__device__ __forceinline__ float crlogf(float x){
  return (float)log((double)x);   // reference-exact (proven R1-R5 absmax=0)
}

// ---------------- kernel 1: sampling -----------------------------------
// argmin_c (-log2 u_c) / p_c  (log2 domain; same argmin as reference argmax)
__global__ __launch_bounds__(256) void k_sample(const float* __restrict__ prob,
                                                u64* __restrict__ planes)
{
  const int tid  = blockIdx.x * 256 + threadIdx.x;
  const int pix  = tid & 0xFFFF;
  const int n    = tid >> 16;
  const int lane = threadIdx.x & 63;

  float p[4], rp[4];
#pragma unroll
  for (int c = 0; c < 4; ++c){
    p[c]  = prob[(((n<<2)|c) << 16) | pix];
    rp[c] = __builtin_amdgcn_rcpf(p[c]);
  }

#pragma unroll 1
  for (int s = 0; s < 10; ++s){
    const uint32_t k0 = KEYS.k0[s];
    const uint32_t k1 = KEYS.k1[s];

    uint32_t mv[4];
    float q[4];
#pragma unroll
    for (int c = 0; c < 4; ++c){
      const uint32_t j = (uint32_t)((((n<<2)|c) << 16) | pix);
      uint32_t x0 = 0u, x1 = j;
      tf2x32(k0, k1, x0, x1);
      const uint32_t m = (x0 ^ x1) >> 9;
      mv[c] = m;
      const float u  = m ? (float)m * 0x1p-23f : 1.17549435e-38f;
      const float l2 = __log2f(u);                  // <= -0.415 for u<0.75
      // poly region u>=0.75: e = 1-u exact (Sterbenz); s_poly = log2(1-e)
      const float e = 1.0f - u;
      float t = -0.14426950408889635f;              // -(1/10)/ln2
      t = fmaf(t, e, -0.16029944898766261f);
      t = fmaf(t, e, -0.18033688011112044f);
      t = fmaf(t, e, -0.20609929155556624f);
      t = fmaf(t, e, -0.24044917348149392f);
      t = fmaf(t, e, -0.28853900817779270f);
      t = fmaf(t, e, -0.36067376022224088f);
      t = fmaf(t, e, -0.48089834696298781f);
      t = fmaf(t, e, -0.72134752044448169f);
      t = fmaf(t, e, -1.4426950408889634f);
      const float sp = e * t;
      const float sv = (m >= 0x600000u) ? sp : l2;  // negative domain
      q[c] = -sv * rp[c];                           // free neg modifier
    }
    // min-network: b1 = min, b2 = 2nd min, first-index tie-break
    const float m01 = fminf(q[0], q[1]), M01 = fmaxf(q[0], q[1]);
    const float m23 = fminf(q[2], q[3]), M23 = fmaxf(q[2], q[3]);
    const float b1 = fminf(m01, m23);
    const float b2 = fminf(fmaxf(m01, m23), fminf(M01, M23));
    int bc = 3;
    bc = (q[2] == b1) ? 2 : bc;
    bc = (q[1] == b1) ? 1 : bc;
    bc = (q[0] == b1) ? 0 : bc;
    // relative margin guard -> exact fallback (bit-identical to reference)
    if ((b2 - b1) < 2e-5f * b2){
      float best = -3.0e38f; bc = 0;
#pragma unroll
      for (int c = 0; c < 4; ++c){
        const uint32_t m = mv[c];
        const float u = m ? (float)m * 0x1p-23f : 1.17549435e-38f;
        const float w = -crlogf(u);
        const float g = -crlogf(w);
        const float sc = g + crlogf(p[c]);
        if (sc > best){ best = sc; bc = c; }
      }
    }

    const int gid = ((n * 10 + s) << 16) | pix;
    const u64 bb0 = __ballot(bc & 1);
    const u64 bb1 = __ballot(bc & 2);
    if (lane == 0){
      planes[((size_t)(gid >> 6) << 1) + 0] = bb0;
      planes[((size_t)(gid >> 6) << 1) + 1] = bb1;
    }
  }
}

// ---------------- kernel 2: fill-bitmap (1024 thr, SWAR seed) -----------
__device__ __forceinline__ void add256(const u64 a[4], const u64 b[4], u64 o[4]){
  u64 c = 0;
#pragma unroll
  for (int w = 0; w < 4; ++w){
    const u64 t = a[w] + c;
    const u64 c1 = (t < c) ? 1ull : 0ull;
    const u64 s = t + b[w];
    const u64 c2 = (s < t) ? 1ull : 0ull;
    o[w] = s;
    c = c1 | c2;
  }
}

__device__ __forceinline__ void runfill(const u64 m[4], const u64 s[4], u64 o[4]){
  u64 A[4];
  add256(m, s, A);
  u64 rm[4], rs[4], RA[4];
#pragma unroll
  for (int w = 0; w < 4; ++w){ rm[w] = __brevll(m[3-w]); rs[w] = __brevll(s[3-w]); }
  add256(rm, rs, RA);
#pragma unroll
  for (int w = 0; w < 4; ++w){
    const u64 up  = (A[w] ^ m[w]) & m[w];
    const u64 rdn = (RA[3-w] ^ rm[3-w]) & rm[3-w];
    o[w] = s[w] | up | __brevll(rdn);
  }
}

__global__ __launch_bounds__(1024) void k_reward(const u64* __restrict__ planes,
                                                 u64* __restrict__ fillB)
{
  const int b   = blockIdx.x;        // 0..239
  const int ns  = b / 3;
  const int cls = (b % 3) + 1;
  const int t   = threadIdx.x;       // 0..1023
  const int r   = t >> 2;            // row
  const int wd  = t & 3;             // word

  __shared__ u64 fgS[256*5];
  __shared__ u64 v0S[256*6], v1S[256*6], v2S[256*6];  // guard cols 0 and 5
  __shared__ u64 fillS[258*5];
  __shared__ u64 bestKey;
  __shared__ int flag;
  __shared__ int flags[2];

  // ---- build fg word ----
  const u64 c0 = (u64)(cls & 1);
  const u64 c1 = (u64)((cls >> 1) & 1);
  const int idxp = (ns << 10) | (r << 2) | wd;
  const ulonglong2 pw = ((const ulonglong2*)planes)[idxp];
  const u64 fg = (c0 ? pw.x : ~pw.x) & (c1 ? pw.y : ~pw.y);
  fgS[r*5 + wd] = fg;
  if (t == 0){ flag = 0; bestKey = 0ull; flags[0] = 0; flags[1] = 0; }
  if (t < 2){
    const int gr = (t == 0) ? 0 : 257;
#pragma unroll
    for (int w = 0; w < 5; ++w) fillS[gr*5 + w] = 0ull;
  }
  __syncthreads();
  if (fg) flag = 1;                  // benign race
  __syncthreads();
  if (!flag) return;                 // empty fg: contribution identically 0

  // ---- vertical 5-sum (bit-sliced, 3 planes) ----
  u64 a0, a1, a2, a3, a4;
  { const int rm2 = r-2, rm1 = r-1, rp1 = r+1, rp2 = r+2;
    a0 = (rm2 >= 0)  ? fgS[rm2*5 + wd] : 0ull;
    a1 = (rm1 >= 0)  ? fgS[rm1*5 + wd] : 0ull;
    a2 = fg;
    a3 = (rp1 < 256) ? fgS[rp1*5 + wd] : 0ull;
    a4 = (rp2 < 256) ? fgS[rp2*5 + wd] : 0ull; }
  u64 v0, v1, v2;
  { const u64 t0 = a0^a1, ca = a0&a1;
    const u64 t1 = t0^a2, cb = t0&a2;
    const u64 t2 = t1^a3, cc = t1&a3;
    v0 = t2^a4;  const u64 cd = t2&a4;
    const u64 w0 = ca^cb, d0 = ca&cb;
    const u64 w1 = cc^cd, d1 = cc&cd;
    v1 = w0^w1;  const u64 d2 = w0&w1;
    v2 = d0|d1|d2; }
  v0S[r*6 + wd + 1] = v0;  v1S[r*6 + wd + 1] = v1;  v2S[r*6 + wd + 1] = v2;
  if (wd == 0){ v0S[r*6] = 0ull; v1S[r*6] = 0ull; v2S[r*6] = 0ull; }
  if (wd == 3){ v0S[r*6+5] = 0ull; v1S[r*6+5] = 0ull; v2S[r*6+5] = 0ull; }
  __syncthreads();

  // ---- horizontal 5-sum of 3-bit-sliced values -> 5 planes h0..h4 ----
  u64 h0, h1, h2, h3, h4;
  {
    const u64 L0 = v0S[r*6+wd], M0 = v0, R0 = v0S[r*6+wd+2];
    const u64 L1 = v1S[r*6+wd], M1 = v1, R1 = v1S[r*6+wd+2];
    const u64 L2 = v2S[r*6+wd], M2 = v2, R2 = v2S[r*6+wd+2];
#define SHP(M,L,R,dx) ((dx) > 0 ? (((M) >> (dx)) | ((R) << (64-(dx)))) \
                                : (((M) << (-(dx))) | ((L) >> (64+(dx)))))
    // P(dx) planes
    const u64 pA0 = SHP(M0,L0,R0,-2), pA1 = SHP(M1,L1,R1,-2), pA2 = SHP(M2,L2,R2,-2);
    const u64 pB0 = SHP(M0,L0,R0,-1), pB1 = SHP(M1,L1,R1,-1), pB2 = SHP(M2,L2,R2,-1);
    const u64 pD0 = SHP(M0,L0,R0, 1), pD1 = SHP(M1,L1,R1, 1), pD2 = SHP(M2,L2,R2, 1);
    const u64 pE0 = SHP(M0,L0,R0, 2), pE1 = SHP(M1,L1,R1, 2), pE2 = SHP(M2,L2,R2, 2);
#undef SHP
    // A = pA + pB  (3b+3b -> 4b)
    u64 A0, A1, A2, A3;
    { u64 c = pA0 & pB0; A0 = pA0 ^ pB0;
      u64 x = pA1 ^ pB1; A1 = x ^ c; c = (pA1 & pB1) | (c & x);
      u64 y = pA2 ^ pB2; A2 = y ^ c; c = (pA2 & pB2) | (c & y);
      A3 = c; }
    // B = pD + pE  (3b+3b -> 4b)
    u64 B0, B1, B2, B3;
    { u64 c = pD0 & pE0; B0 = pD0 ^ pE0;
      u64 x = pD1 ^ pE1; B1 = x ^ c; c = (pD1 & pE1) | (c & x);
      u64 y = pD2 ^ pE2; B2 = y ^ c; c = (pD2 & pE2) | (c & y);
      B3 = c; }
    // C = A + B  (4b+4b -> 5b)
    u64 C0, C1, C2, C3, C4;
    { u64 c = A0 & B0; C0 = A0 ^ B0;
      u64 x = A1 ^ B1; C1 = x ^ c; c = (A1 & B1) | (c & x);
      u64 y = A2 ^ B2; C2 = y ^ c; c = (A2 & B2) | (c & y);
      u64 z = A3 ^ B3; C3 = z ^ c; c = (A3 & B3) | (c & z);
      C4 = c; }
    // H = C + M  (5b+3b -> 5b, max 25)
    { u64 c = C0 & M0; h0 = C0 ^ M0;
      u64 x = C1 ^ M1; h1 = x ^ c; c = (C1 & M1) | (c & x);
      u64 y = C2 ^ M2; h2 = y ^ c; c = (C2 & M2) | (c & y);
      h3 = C3 ^ c; c = C3 & c;
      h4 = C4 ^ c; }
  }

  // ---- masked bit-sliced max + first-index argmax ----
  u64 myKey = 0ull;
  if (fg){
    u64 cand = fg; unsigned maxv = 0u;
    u64 tt;
    tt = cand & h4; if (tt){ cand = tt; maxv |= 16u; }
    tt = cand & h3; if (tt){ cand = tt; maxv |= 8u; }
    tt = cand & h2; if (tt){ cand = tt; maxv |= 4u; }
    tt = cand & h1; if (tt){ cand = tt; maxv |= 2u; }
    tt = cand & h0; if (tt){ cand = tt; maxv |= 1u; }
    const int bit = __builtin_ctzll(cand);
    const unsigned idx = (unsigned)((r << 8) | (wd << 6) | bit);
    myKey = ((u64)maxv << 32) | (u64)(0xFFFFFFFFu - idx);
  }
#pragma unroll
  for (int off = 32; off; off >>= 1){
    const u64 o = (u64)__shfl_xor((long long)myKey, off, 64);
    if (o > myKey) myKey = o;
  }
  if ((t & 63) == 0) atomicMax(&bestKey, myKey);
  __syncthreads();
  const int seedIdx = (int)(0xFFFFFFFFu - (unsigned)(bestKey & 0xFFFFFFFFull));
  const int srow = seedIdx >> 8, scol = seedIdx & 255;

  // ---- scanline flood fill (rows on threads 0..255, 2 barriers/iter) ----
  u64 f[4] = {0ull,0ull,0ull,0ull};
  u64 g[4] = {0ull,0ull,0ull,0ull};
  if (t < 256){
#pragma unroll
    for (int w = 0; w < 4; ++w) g[w] = fgS[t*5 + w];
    if (t == srow) f[scol >> 6] = 1ull << (scol & 63);
#pragma unroll
    for (int w = 0; w < 4; ++w) fillS[(t+1)*5 + w] = f[w];
  }
  __syncthreads();   // fill init + flags init visible

  int it = 0;
  for (;;){
    bool ch = false;
    u64 nf[4];
    if (t < 256){
      u64 U[4], S[4];
#pragma unroll
      for (int w = 0; w < 4; ++w)
        U[w] = fillS[t*5 + w] | fillS[(t+1)*5 + w] | fillS[(t+2)*5 + w];
      S[0] = U[0] | (U[0]<<1) | (U[0]>>1) | (U[1]<<63);
      S[1] = U[1] | (U[1]<<1) | (U[1]>>1) | (U[0]>>63) | (U[2]<<63);
      S[2] = U[2] | (U[2]<<1) | (U[2]>>1) | (U[1]>>63) | (U[3]<<63);
      S[3] = U[3] | (U[3]<<1) | (U[3]>>1) | (U[2]>>63);
#pragma unroll
      for (int w = 0; w < 4; ++w) S[w] &= g[w];
      runfill(g, S, nf);
#pragma unroll
      for (int w = 0; w < 4; ++w){ ch |= (nf[w] != f[w]); f[w] = nf[w]; }
    }
    __syncthreads();   // phase-1 reads done
    if (t < 256){
#pragma unroll
      for (int w = 0; w < 4; ++w) fillS[(t+1)*5 + w] = f[w];
    }
    if (ch) flags[it & 1] = 1;
    if (t == 0) flags[(it + 1) & 1] = 0;   // safe: separated from its readers by barriers
    __syncthreads();   // writes + flag visible
    if (!flags[it & 1]) break;
    ++it;
  }

  // ---- dump fill bitmap ----
  if (t < 256){
    const int nsc = ns*3 + (cls - 1);
    u64* fb = fillB + (((size_t)nsc) << 10) + (t << 2);
#pragma unroll
    for (int w = 0; w < 4; ++w) fb[w] = f[w];
  }
}

// ---------------- kernel 3: output write --------------------------------
__global__ __launch_bounds__(256) void k_write(const u64* __restrict__ planes,
                                               const u64* __restrict__ fillB,
                                               const float* __restrict__ prob,
                                               float* __restrict__ out)
{
  const int T = blockIdx.x * 256 + threadIdx.x;
  const int lane = T & 63;
#pragma unroll
  for (int i = 0; i < 10; ++i){
    const int g  = i * 524288 + T;
    const int wi = g >> 6;
    const u64 pw0 = planes[(size_t)wi*2 + 0];
    const u64 pw1 = planes[(size_t)wi*2 + 1];
    const int ns = g >> 16;
    const int n  = ns / 10;
    const int pp = g & 0xFFFF;
    const int fwi = pp >> 6;
    const u64 f1 = fillB[(((size_t)(ns*3 + 0)) << 10) | fwi];
    const u64 f2 = fillB[(((size_t)(ns*3 + 1)) << 10) | fwi];
    const u64 f3 = fillB[(((size_t)(ns*3 + 2)) << 10) | fwi];
    const float pa = prob[(size_t)((((n<<2)|1) << 16) | pp)];
    const float pb = prob[(size_t)((((n<<2)|2) << 16) | pp)];
    const float pc = prob[(size_t)((((n<<2)|3) << 16) | pp)];
    const int cls = (int)((pw0 >> lane) & 1ull) | (((int)((pw1 >> lane) & 1ull)) << 1);
    const u64   fw = (cls == 1) ? f1 : ((cls == 2) ? f2 : f3);
    const float p  = (cls == 1) ? pa : ((cls == 2) ? pb : pc);
    const uint32_t sgn = ((uint32_t)((fw >> lane) & 1ull)) << 31;
    float o = __uint_as_float(__float_as_uint(p) ^ sgn);
    if (cls == 0) o = 0.0f;
    out[g] = o;
  }
}

extern "C" void kernel_launch(void* const* d_in, const int* in_sizes, int n_in,
                              void* d_out, int out_size, void* d_ws, size_t ws_size,
                              hipStream_t stream)
{
  const float* prob = (const float*)d_in[0];
  float* out = (float*)d_out;
  u64* planes = (u64*)d_ws;            // 1.31 MB
  u64* fillB  = planes + 163840;       // 1.97 MB

  k_sample<<<2048, 256, 0, stream>>>(prob, planes);
  k_reward<<<240, 1024, 0, stream>>>(planes, fillB);
  k_write <<<2048, 256, 0, stream>>>(planes, fillB, prob, out);
}

// Round 7
// 89.523 us; speedup vs baseline: 3.4546x; 1.0135x over previous
//
#include <hip/hip_runtime.h>
#include <cstdint>
#include <cstddef>

typedef unsigned long long u64;

// 1-instruction rotate
#if defined(__HIP_DEVICE_COMPILE__)
#define ROTL(x, r) __builtin_amdgcn_alignbit((x), (x), 32 - (r))
#else
#define ROTL(x, r) (((x) << (r)) | ((x) >> (32 - (r))))
#endif

// guaranteed-native log2 (v_log_f32, 1 inst, quarter-rate)
__device__ __forceinline__ float fast_log2(float x){
  float r;
  asm("v_log_f32 %0, %1" : "=v"(r) : "v"(x));
  return r;
}

// ---------------- threefry2x32 (20 rounds) ------------------------------
__device__ __forceinline__ void tf2x32(uint32_t k0, uint32_t k1, uint32_t& x0, uint32_t& x1){
  const uint32_t k2 = k0 ^ k1 ^ 0x1BD11BDAu;
  x0 += k0; x1 += k1;
#define TFR(r) { x0 += x1; x1 = ROTL(x1, r); x1 ^= x0; }
  TFR(13) TFR(15) TFR(26) TFR(6)
  x0 += k1; x1 += k2 + 1u;
  TFR(17) TFR(29) TFR(16) TFR(24)
  x0 += k2; x1 += k0 + 2u;
  TFR(13) TFR(15) TFR(26) TFR(6)
  x0 += k0; x1 += k1 + 3u;
  TFR(17) TFR(29) TFR(16) TFR(24)
  x0 += k1; x1 += k2 + 4u;
  TFR(13) TFR(15) TFR(26) TFR(6)
  x0 += k2; x1 += k0 + 5u;
#undef TFR
}

constexpr void tf2x32_h(uint32_t k0, uint32_t k1, uint32_t& x0, uint32_t& x1){
  const uint32_t k2 = k0 ^ k1 ^ 0x1BD11BDAu;
  x0 += k0; x1 += k1;
#define TFR(r) { x0 += x1; x1 = ((x1<<(r))|(x1>>(32-(r)))); x1 ^= x0; }
  TFR(13) TFR(15) TFR(26) TFR(6)
  x0 += k1; x1 += k2 + 1u;
  TFR(17) TFR(29) TFR(16) TFR(24)
  x0 += k2; x1 += k0 + 2u;
  TFR(13) TFR(15) TFR(26) TFR(6)
  x0 += k0; x1 += k1 + 3u;
  TFR(17) TFR(29) TFR(16) TFR(24)
  x0 += k1; x1 += k2 + 4u;
  TFR(13) TFR(15) TFR(26) TFR(6)
  x0 += k2; x1 += k0 + 5u;
#undef TFR
}

struct Keys { uint32_t k0[10]; uint32_t k1[10]; };
constexpr Keys make_keys(){
  Keys K{};
  for (int s = 0; s < 10; ++s){
    uint32_t x0 = 0u, x1 = (uint32_t)s;
    tf2x32_h(0u, 42u, x0, x1);
    K.k0[s] = x0; K.k1[s] = x1;
  }
  return K;
}
__constant__ constexpr Keys KEYS = make_keys();

__device__ __forceinline__ float crlogf(float x){
  return (float)log((double)x);   // reference-exact (proven R1-R6 absmax=0)
}

// ---------------- kernel 1: sampling -----------------------------------
// argmin_c (-log2 u_c) / p_c  (same argmin as reference argmax)
__global__ __launch_bounds__(256) void k_sample(const float* __restrict__ prob,
                                                u64* __restrict__ planes)
{
  const int tid  = blockIdx.x * 256 + threadIdx.x;
  const int pix  = tid & 0xFFFF;
  const int n    = tid >> 16;
  const int lane = threadIdx.x & 63;

  float p[4], rp[4];
  uint32_t jc[4];
#pragma unroll
  for (int c = 0; c < 4; ++c){
    jc[c] = (uint32_t)((((n<<2)|c) << 16) | pix);
    p[c]  = prob[jc[c]];
    rp[c] = __builtin_amdgcn_rcpf(p[c]);
  }

#pragma unroll 2
  for (int s = 0; s < 10; ++s){
    const uint32_t k0 = KEYS.k0[s];
    const uint32_t k1 = KEYS.k1[s];

    uint32_t mv[4];
    float q[4];
#pragma unroll
    for (int c = 0; c < 4; ++c){
      uint32_t x0 = 0u, x1 = jc[c];
      tf2x32(k0, k1, x0, x1);
      const uint32_t m = (x0 ^ x1) >> 9;
      mv[c] = m;
      // u = m*2^-23, or FLT_MIN when m==0 (0*x=0, fmax picks FLT_MIN)
      const float u  = fmaxf((float)m * 0x1p-23f, 1.17549435e-38f);
      const float l2 = fast_log2(u);                // native v_log_f32
      // poly region u>=0.75: e = 1-u exact (Sterbenz); sp = log2(1-e)
      const float e = 1.0f - u;
      float t = -0.14426950408889635f;              // -(1/10)/ln2
      t = fmaf(t, e, -0.16029944898766261f);
      t = fmaf(t, e, -0.18033688011112044f);
      t = fmaf(t, e, -0.20609929155556624f);
      t = fmaf(t, e, -0.24044917348149392f);
      t = fmaf(t, e, -0.28853900817779270f);
      t = fmaf(t, e, -0.36067376022224088f);
      t = fmaf(t, e, -0.48089834696298781f);
      t = fmaf(t, e, -0.72134752044448169f);
      t = fmaf(t, e, -1.4426950408889634f);
      const float sp = e * t;
      const float sv = (m >= 0x600000u) ? sp : l2;  // negative domain
      q[c] = -sv * rp[c];
    }
    // min-network: b1 = min, b2 = 2nd min, first-index tie-break
    const float m01 = fminf(q[0], q[1]), M01 = fmaxf(q[0], q[1]);
    const float m23 = fminf(q[2], q[3]), M23 = fmaxf(q[2], q[3]);
    const float b1 = fminf(m01, m23);
    const float b2 = fminf(fmaxf(m01, m23), fminf(M01, M23));
    int bc = 3;
    bc = (q[2] == b1) ? 2 : bc;
    bc = (q[1] == b1) ? 1 : bc;
    bc = (q[0] == b1) ? 0 : bc;
    // relative margin guard -> exact fallback (bit-identical to reference)
    if ((b2 - b1) < 2e-5f * b2){
      float best = -3.0e38f; bc = 0;
#pragma unroll
      for (int c = 0; c < 4; ++c){
        const uint32_t m = mv[c];
        const float u = m ? (float)m * 0x1p-23f : 1.17549435e-38f;
        const float w = -crlogf(u);
        const float g = -crlogf(w);
        const float sc = g + crlogf(p[c]);
        if (sc > best){ best = sc; bc = c; }
      }
    }

    const int gid = ((n * 10 + s) << 16) | pix;
    const u64 bb0 = __ballot(bc & 1);
    const u64 bb1 = __ballot(bc & 2);
    if (lane == 0){
      planes[((size_t)(gid >> 6) << 1) + 0] = bb0;
      planes[((size_t)(gid >> 6) << 1) + 1] = bb1;
    }
  }
}

// ---------------- kernel 2: fill-bitmap (1024 thr, SWAR seed) -----------
__device__ __forceinline__ void add256(const u64 a[4], const u64 b[4], u64 o[4]){
  u64 c = 0;
#pragma unroll
  for (int w = 0; w < 4; ++w){
    const u64 t = a[w] + c;
    const u64 c1 = (t < c) ? 1ull : 0ull;
    const u64 s = t + b[w];
    const u64 c2 = (s < t) ? 1ull : 0ull;
    o[w] = s;
    c = c1 | c2;
  }
}

__device__ __forceinline__ void runfill(const u64 m[4], const u64 s[4], u64 o[4]){
  u64 A[4];
  add256(m, s, A);
  u64 rm[4], rs[4], RA[4];
#pragma unroll
  for (int w = 0; w < 4; ++w){ rm[w] = __brevll(m[3-w]); rs[w] = __brevll(s[3-w]); }
  add256(rm, rs, RA);
#pragma unroll
  for (int w = 0; w < 4; ++w){
    const u64 up  = (A[w] ^ m[w]) & m[w];
    const u64 rdn = (RA[3-w] ^ rm[3-w]) & rm[3-w];
    o[w] = s[w] | up | __brevll(rdn);
  }
}

__global__ __launch_bounds__(1024) void k_reward(const u64* __restrict__ planes,
                                                 u64* __restrict__ fillB)
{
  const int b   = blockIdx.x;        // 0..239
  const int ns  = b / 3;
  const int cls = (b % 3) + 1;
  const int t   = threadIdx.x;       // 0..1023
  const int r   = t >> 2;            // row
  const int wd  = t & 3;             // word

  __shared__ u64 fgS[256*5];
  __shared__ u64 v0S[256*6], v1S[256*6], v2S[256*6];
  __shared__ u64 fillS[258*5];
  __shared__ u64 bestKey;
  __shared__ int flag;
  __shared__ int flags[2];

  const u64 c0 = (u64)(cls & 1);
  const u64 c1 = (u64)((cls >> 1) & 1);
  const int idxp = (ns << 10) | (r << 2) | wd;
  const ulonglong2 pw = ((const ulonglong2*)planes)[idxp];
  const u64 fg = (c0 ? pw.x : ~pw.x) & (c1 ? pw.y : ~pw.y);
  fgS[r*5 + wd] = fg;
  if (t == 0){ flag = 0; bestKey = 0ull; flags[0] = 0; flags[1] = 0; }
  if (t < 2){
    const int gr = (t == 0) ? 0 : 257;
#pragma unroll
    for (int w = 0; w < 5; ++w) fillS[gr*5 + w] = 0ull;
  }
  __syncthreads();
  if (fg) flag = 1;                  // benign race
  __syncthreads();
  if (!flag) return;

  // ---- vertical 5-sum (bit-sliced, 3 planes) ----
  u64 a0, a1, a2, a3, a4;
  { const int rm2 = r-2, rm1 = r-1, rp1 = r+1, rp2 = r+2;
    a0 = (rm2 >= 0)  ? fgS[rm2*5 + wd] : 0ull;
    a1 = (rm1 >= 0)  ? fgS[rm1*5 + wd] : 0ull;
    a2 = fg;
    a3 = (rp1 < 256) ? fgS[rp1*5 + wd] : 0ull;
    a4 = (rp2 < 256) ? fgS[rp2*5 + wd] : 0ull; }
  u64 v0, v1, v2;
  { const u64 t0 = a0^a1, ca = a0&a1;
    const u64 t1 = t0^a2, cb = t0&a2;
    const u64 t2 = t1^a3, cc = t1&a3;
    v0 = t2^a4;  const u64 cd = t2&a4;
    const u64 w0 = ca^cb, d0 = ca&cb;
    const u64 w1 = cc^cd, d1 = cc&cd;
    v1 = w0^w1;  const u64 d2 = w0&w1;
    v2 = d0|d1|d2; }
  v0S[r*6 + wd + 1] = v0;  v1S[r*6 + wd + 1] = v1;  v2S[r*6 + wd + 1] = v2;
  if (wd == 0){ v0S[r*6] = 0ull; v1S[r*6] = 0ull; v2S[r*6] = 0ull; }
  if (wd == 3){ v0S[r*6+5] = 0ull; v1S[r*6+5] = 0ull; v2S[r*6+5] = 0ull; }
  __syncthreads();

  // ---- horizontal 5-sum -> 5 planes h0..h4 ----
  u64 h0, h1, h2, h3, h4;
  {
    const u64 L0 = v0S[r*6+wd], M0 = v0, R0 = v0S[r*6+wd+2];
    const u64 L1 = v1S[r*6+wd], M1 = v1, R1 = v1S[r*6+wd+2];
    const u64 L2 = v2S[r*6+wd], M2 = v2, R2 = v2S[r*6+wd+2];
#define SHP(M,L,R,dx) ((dx) > 0 ? (((M) >> (dx)) | ((R) << (64-(dx)))) \
                                : (((M) << (-(dx))) | ((L) >> (64+(dx)))))
    const u64 pA0 = SHP(M0,L0,R0,-2), pA1 = SHP(M1,L1,R1,-2), pA2 = SHP(M2,L2,R2,-2);
    const u64 pB0 = SHP(M0,L0,R0,-1), pB1 = SHP(M1,L1,R1,-1), pB2 = SHP(M2,L2,R2,-1);
    const u64 pD0 = SHP(M0,L0,R0, 1), pD1 = SHP(M1,L1,R1, 1), pD2 = SHP(M2,L2,R2, 1);
    const u64 pE0 = SHP(M0,L0,R0, 2), pE1 = SHP(M1,L1,R1, 2), pE2 = SHP(M2,L2,R2, 2);
#undef SHP
    u64 A0, A1, A2, A3;
    { u64 c = pA0 & pB0; A0 = pA0 ^ pB0;
      u64 x = pA1 ^ pB1; A1 = x ^ c; c = (pA1 & pB1) | (c & x);
      u64 y = pA2 ^ pB2; A2 = y ^ c; c = (pA2 & pB2) | (c & y);
      A3 = c; }
    u64 B0, B1, B2, B3;
    { u64 c = pD0 & pE0; B0 = pD0 ^ pE0;
      u64 x = pD1 ^ pE1; B1 = x ^ c; c = (pD1 & pE1) | (c & x);
      u64 y = pD2 ^ pE2; B2 = y ^ c; c = (pD2 & pE2) | (c & y);
      B3 = c; }
    u64 C0, C1, C2, C3, C4;
    { u64 c = A0 & B0; C0 = A0 ^ B0;
      u64 x = A1 ^ B1; C1 = x ^ c; c = (A1 & B1) | (c & x);
      u64 y = A2 ^ B2; C2 = y ^ c; c = (A2 & B2) | (c & y);
      u64 z = A3 ^ B3; C3 = z ^ c; c = (A3 & B3) | (c & z);
      C4 = c; }
    { u64 c = C0 & M0; h0 = C0 ^ M0;
      u64 x = C1 ^ M1; h1 = x ^ c; c = (C1 & M1) | (c & x);
      u64 y = C2 ^ M2; h2 = y ^ c; c = (C2 & M2) | (c & y);
      h3 = C3 ^ c; c = C3 & c;
      h4 = C4 ^ c; }
  }

  // ---- masked bit-sliced max + first-index argmax ----
  u64 myKey = 0ull;
  if (fg){
    u64 cand = fg; unsigned maxv = 0u;
    u64 tt;
    tt = cand & h4; if (tt){ cand = tt; maxv |= 16u; }
    tt = cand & h3; if (tt){ cand = tt; maxv |= 8u; }
    tt = cand & h2; if (tt){ cand = tt; maxv |= 4u; }
    tt = cand & h1; if (tt){ cand = tt; maxv |= 2u; }
    tt = cand & h0; if (tt){ cand = tt; maxv |= 1u; }
    const int bit = __builtin_ctzll(cand);
    const unsigned idx = (unsigned)((r << 8) | (wd << 6) | bit);
    myKey = ((u64)maxv << 32) | (u64)(0xFFFFFFFFu - idx);
  }
#pragma unroll
  for (int off = 32; off; off >>= 1){
    const u64 o = (u64)__shfl_xor((long long)myKey, off, 64);
    if (o > myKey) myKey = o;
  }
  if ((t & 63) == 0) atomicMax(&bestKey, myKey);
  __syncthreads();
  const int seedIdx = (int)(0xFFFFFFFFu - (unsigned)(bestKey & 0xFFFFFFFFull));
  const int srow = seedIdx >> 8, scol = seedIdx & 255;

  // ---- scanline flood fill ----
  u64 f[4] = {0ull,0ull,0ull,0ull};
  u64 g[4] = {0ull,0ull,0ull,0ull};
  if (t < 256){
#pragma unroll
    for (int w = 0; w < 4; ++w) g[w] = fgS[t*5 + w];
    if (t == srow) f[scol >> 6] = 1ull << (scol & 63);
#pragma unroll
    for (int w = 0; w < 4; ++w) fillS[(t+1)*5 + w] = f[w];
  }
  __syncthreads();

  int it = 0;
  for (;;){
    bool ch = false;
    u64 nf[4];
    if (t < 256){
      u64 U[4], S[4];
#pragma unroll
      for (int w = 0; w < 4; ++w)
        U[w] = fillS[t*5 + w] | fillS[(t+1)*5 + w] | fillS[(t+2)*5 + w];
      S[0] = U[0] | (U[0]<<1) | (U[0]>>1) | (U[1]<<63);
      S[1] = U[1] | (U[1]<<1) | (U[1]>>1) | (U[0]>>63) | (U[2]<<63);
      S[2] = U[2] | (U[2]<<1) | (U[2]>>1) | (U[1]>>63) | (U[3]<<63);
      S[3] = U[3] | (U[3]<<1) | (U[3]>>1) | (U[2]>>63);
#pragma unroll
      for (int w = 0; w < 4; ++w) S[w] &= g[w];
      runfill(g, S, nf);
#pragma unroll
      for (int w = 0; w < 4; ++w){ ch |= (nf[w] != f[w]); f[w] = nf[w]; }
    }
    __syncthreads();
    if (t < 256){
#pragma unroll
      for (int w = 0; w < 4; ++w) fillS[(t+1)*5 + w] = f[w];
    }
    if (ch) flags[it & 1] = 1;
    if (t == 0) flags[(it + 1) & 1] = 0;
    __syncthreads();
    if (!flags[it & 1]) break;
    ++it;
  }

  if (t < 256){
    const int nsc = ns*3 + (cls - 1);
    u64* fb = fillB + (((size_t)nsc) << 10) + (t << 2);
#pragma unroll
    for (int w = 0; w < 4; ++w) fb[w] = f[w];
  }
}

// ---------------- kernel 3: output write --------------------------------
__global__ __launch_bounds__(256) void k_write(const u64* __restrict__ planes,
                                               const u64* __restrict__ fillB,
                                               const float* __restrict__ prob,
                                               float* __restrict__ out)
{
  const int T = blockIdx.x * 256 + threadIdx.x;
  const int lane = T & 63;
#pragma unroll
  for (int i = 0; i < 10; ++i){
    const int g  = i * 524288 + T;
    const int wi = g >> 6;
    const u64 pw0 = planes[(size_t)wi*2 + 0];
    const u64 pw1 = planes[(size_t)wi*2 + 1];
    const int ns = g >> 16;
    const int n  = ns / 10;
    const int pp = g & 0xFFFF;
    const int fwi = pp >> 6;
    const u64 f1 = fillB[(((size_t)(ns*3 + 0)) << 10) | fwi];
    const u64 f2 = fillB[(((size_t)(ns*3 + 1)) << 10) | fwi];
    const u64 f3 = fillB[(((size_t)(ns*3 + 2)) << 10) | fwi];
    const float pa = prob[(size_t)((((n<<2)|1) << 16) | pp)];
    const float pb = prob[(size_t)((((n<<2)|2) << 16) | pp)];
    const float pc = prob[(size_t)((((n<<2)|3) << 16) | pp)];
    const int cls = (int)((pw0 >> lane) & 1ull) | (((int)((pw1 >> lane) & 1ull)) << 1);
    const u64   fw = (cls == 1) ? f1 : ((cls == 2) ? f2 : f3);
    const float p  = (cls == 1) ? pa : ((cls == 2) ? pb : pc);
    const uint32_t sgn = ((uint32_t)((fw >> lane) & 1ull)) << 31;
    float o = __uint_as_float(__float_as_uint(p) ^ sgn);
    if (cls == 0) o = 0.0f;
    out[g] = o;
  }
}

extern "C" void kernel_launch(void* const* d_in, const int* in_sizes, int n_in,
                              void* d_out, int out_size, void* d_ws, size_t ws_size,
                              hipStream_t stream)
{
  const float* prob = (const float*)d_in[0];
  float* out = (float*)d_out;
  u64* planes = (u64*)d_ws;            // 1.31 MB
  u64* fillB  = planes + 163840;       // 1.97 MB

  k_sample<<<2048, 256, 0, stream>>>(prob, planes);
  k_reward<<<240, 1024, 0, stream>>>(planes, fillB);
  k_write <<<2048, 256, 0, stream>>>(planes, fillB, prob, out);
}